// Round 1
// baseline (6683.845 us; speedup 1.0000x reference)
//
#include <hip/hip_runtime.h>
#include <math.h>

#define N_PTS 8192
#define BATCH 2
#define M_CTR 2048
#define KNB   32
#define CIN   64
#define CH    128
#define NHEAD 8
#define DH    16

// ---------------------------------------------------------------------------
// FPS: one block per batch, 1024 threads, xyz + mind fully resident (LDS/regs).
// Exact f32 arithmetic (no FMA contraction) + first-index tie-break to match
// the numpy/JAX reference bitwise (discrete output!).
// ---------------------------------------------------------------------------
__global__ __launch_bounds__(1024) void fps_kernel(const float* __restrict__ xyz,
                                                   int* __restrict__ ctrIdx,
                                                   float* __restrict__ outCtr) {
  __shared__ float sx[N_PTS];
  __shared__ float sy[N_PTS];
  __shared__ float sz[N_PTS];
  __shared__ int   cidx[M_CTR];
  __shared__ float rv[16];
  __shared__ int   rp[16];
  __shared__ int   sLast;

  const int b = blockIdx.x;
  const int t = threadIdx.x;
  const float* xb = xyz + (size_t)b * N_PTS * 3;
  for (int i = t; i < N_PTS * 3; i += 1024) {
    float v = xb[i];
    int pt = i / 3;
    int d  = i - pt * 3;
    if (d == 0) sx[pt] = v;
    else if (d == 1) sy[pt] = v;
    else sz[pt] = v;
  }
  __syncthreads();

  float mind[8];
#pragma unroll
  for (int s = 0; s < 8; ++s) mind[s] = INFINITY;
  int last = 0;
  for (int m = 0; m < M_CTR; ++m) {
    if (t == 0) cidx[m] = last;
    float lx = sx[last], ly = sy[last], lz = sz[last];
    float bv = -INFINITY;
    int   bp = 0x7fffffff;
#pragma unroll
    for (int s = 0; s < 8; ++s) {
      int pt = t + s * 1024;
      float dx = __fsub_rn(sx[pt], lx);
      float dy = __fsub_rn(sy[pt], ly);
      float dz = __fsub_rn(sz[pt], lz);
      float d2 = __fadd_rn(__fadd_rn(__fmul_rn(dx, dx), __fmul_rn(dy, dy)),
                           __fmul_rn(dz, dz));
      float mn = fminf(mind[s], d2);
      mind[s] = mn;
      if (mn > bv) { bv = mn; bp = pt; }   // ascending pt => strict > keeps first
    }
    // wave butterfly argmax (larger value wins; tie -> smaller index)
#pragma unroll
    for (int off = 1; off < 64; off <<= 1) {
      float ov = __shfl_xor(bv, off, 64);
      int   op = __shfl_xor(bp, off, 64);
      if (ov > bv || (ov == bv && op < bp)) { bv = ov; bp = op; }
    }
    const int wv = t >> 6;
    if ((t & 63) == 0) { rv[wv] = bv; rp[wv] = bp; }
    __syncthreads();
    if (wv == 0) {
      float v2 = (t < 16) ? rv[t] : -INFINITY;
      int   p2 = (t < 16) ? rp[t] : 0x7fffffff;
#pragma unroll
      for (int off = 1; off < 16; off <<= 1) {
        float ov = __shfl_xor(v2, off, 64);
        int   op = __shfl_xor(p2, off, 64);
        if (ov > v2 || (ov == v2 && op < p2)) { v2 = ov; p2 = op; }
      }
      if (t == 0) sLast = p2;
    }
    __syncthreads();
    last = sLast;
  }
  __syncthreads();
  for (int m = t; m < M_CTR; m += 1024) {
    int ci = cidx[m];
    ctrIdx[b * M_CTR + m] = ci;
    float* o = outCtr + (size_t)(b * M_CTR + m) * 3;
    o[0] = sx[ci]; o[1] = sy[ci]; o[2] = sz[ci];
  }
}

// ---------------------------------------------------------------------------
// Ball query: one wave per center; first K=32 indices in ascending order with
// d2 < 0.25 (exact f32, no contraction). raw idx = -1 for pad slots.
// ---------------------------------------------------------------------------
__global__ __launch_bounds__(256) void ballq_kernel(const float* __restrict__ xyz,
                                                    const int* __restrict__ ctrIdx,
                                                    int* __restrict__ rawIdx) {
  const int cm   = blockIdx.x * 4 + (threadIdx.x >> 6);
  const int lane = threadIdx.x & 63;
  const int b    = cm >> 11;
  const float* xb = xyz + (size_t)b * N_PTS * 3;
  const int ci = ctrIdx[cm];
  const float cx = xb[ci * 3 + 0], cy = xb[ci * 3 + 1], cz = xb[ci * 3 + 2];
  int* out = rawIdx + (size_t)cm * KNB;
  int have = 0;
  for (int base = 0; base < N_PTS; base += 64) {
    int pt = base + lane;
    float dx = __fsub_rn(cx, xb[pt * 3 + 0]);
    float dy = __fsub_rn(cy, xb[pt * 3 + 1]);
    float dz = __fsub_rn(cz, xb[pt * 3 + 2]);
    float d2 = __fadd_rn(__fadd_rn(__fmul_rn(dx, dx), __fmul_rn(dy, dy)),
                         __fmul_rn(dz, dz));
    bool hit = d2 < 0.25f;
    unsigned long long mask = __ballot(hit);
    if (hit) {
      int rank = have + __popcll(mask & ((1ull << lane) - 1ull));
      if (rank < KNB) out[rank] = pt;
    }
    have += __popcll(mask);
    if (have >= KNB) break;
  }
  if (lane < KNB && lane >= have) out[lane] = -1;
}

// ---------------------------------------------------------------------------
// Fused per-center transformer. One block (256 thr) per center.
// Thread (t): row r = t&31 (neighbor slot), col group g = t>>5 owns cols
// [g*16, g*16+16). All [32][128] LDS tiles padded to 129 (bank conflicts).
// ---------------------------------------------------------------------------
struct SAParams {
  const float* xyz; const float* feats;
  const float* W_in; const float* b_in; const float* ln_in_g; const float* ln_in_b;
  const float* W_pos; const float* b_pos;
  const float* Wq; const float* bq; const float* Wk; const float* bk;
  const float* Wv; const float* bv; const float* Wo; const float* bo;
  const float* ln1_g; const float* ln1_b;
  const float* W1; const float* b1; const float* W2; const float* b2;
  const float* ln2_g; const float* ln2_b; const float* out_g; const float* out_b;
  const int* ctrIdx; const int* rawIdx;
  float* out;
};

__device__ __forceinline__ void fma16(float a, const float* __restrict__ w,
                                      float* acc) {
  const float4* w4 = (const float4*)w;
#pragma unroll
  for (int q4 = 0; q4 < 4; ++q4) {
    float4 wv = w4[q4];
    acc[q4 * 4 + 0] = fmaf(a, wv.x, acc[q4 * 4 + 0]);
    acc[q4 * 4 + 1] = fmaf(a, wv.y, acc[q4 * 4 + 1]);
    acc[q4 * 4 + 2] = fmaf(a, wv.z, acc[q4 * 4 + 2]);
    acc[q4 * 4 + 3] = fmaf(a, wv.w, acc[q4 * 4 + 3]);
  }
}

__global__ __launch_bounds__(256, 2) void sa_kernel(SAParams p) {
  __shared__ float xs[KNB][CH + 1];
  __shared__ float qs[KNB][CH + 1];
  __shared__ float ksb[KNB][CH + 1];
  __shared__ float vsb[KNB][CH + 1];
  __shared__ float sb[KNB][KNB + 1];
  __shared__ float ob[KNB][DH];
  __shared__ float redS[KNB][8];
  __shared__ float redQ[KNB][8];
  __shared__ float mrow[KNB];
  __shared__ float irow[KNB];
  __shared__ float pstat[2];
  __shared__ int   nidx[KNB];
  __shared__ int   padf[KNB];
  __shared__ float nx[KNB], ny[KNB], nz[KNB];

  const int t  = threadIdx.x;
  const int r  = t & 31;
  const int g  = t >> 5;
  const int c0 = g * DH;
  const int cm = blockIdx.x;
  const int b  = cm >> 11;

  if (t < KNB) {
    int raw = p.rawIdx[(size_t)cm * KNB + t];
    int ci  = p.ctrIdx[cm];
    int ni  = (raw < 0) ? ci : raw;
    nidx[t] = ni;
    padf[t] = (raw < 0) ? 1 : 0;
    const float* q = p.xyz + ((size_t)b * N_PTS + ni) * 3;
    nx[t] = q[0]; ny[t] = q[1]; nz[t] = q[2];
  }
  __syncthreads();

  // gather feats into qs rows (used as [32][64] scratch)
  for (int e = t; e < KNB * CIN; e += 256) {
    int rr = e >> 6, cc = e & 63;
    qs[rr][cc] = p.feats[((size_t)b * N_PTS + nidx[rr]) * CIN + cc];
  }
  __syncthreads();

  float acc[DH];
  // ---- input projection: h = feats @ W_in + b_in ----
#pragma unroll
  for (int i = 0; i < DH; ++i) acc[i] = p.b_in[c0 + i];
  for (int k = 0; k < CIN; ++k)
    fma16(qs[r][k], p.W_in + (size_t)k * CH + c0, acc);
  // LN(ln_in) + relu + pos-enc -> xs
  {
    float s = 0.f, sq = 0.f;
#pragma unroll
    for (int i = 0; i < DH; ++i) { s += acc[i]; sq += acc[i] * acc[i]; }
    redS[r][g] = s; redQ[r][g] = sq;
  }
  __syncthreads();
  if (t < KNB) {
    float s = 0.f, sq = 0.f;
#pragma unroll
    for (int gg = 0; gg < 8; ++gg) { s += redS[t][gg]; sq += redQ[t][gg]; }
    float mean = s * (1.0f / CH);
    float var  = fmaxf(sq * (1.0f / CH) - mean * mean, 0.f);
    mrow[t] = mean; irow[t] = rsqrtf(var + 1e-5f);
  }
  __syncthreads();
  {
    float mean = mrow[r], inv = irow[r];
    float px = nx[r], py = ny[r], pz = nz[r];
#pragma unroll
    for (int i = 0; i < DH; ++i) {
      int c = c0 + i;
      float h = (acc[i] - mean) * inv * p.ln_in_g[c] + p.ln_in_b[c];
      h = fmaxf(h, 0.f);
      float pos = p.b_pos[c];
      pos = fmaf(px, p.W_pos[0 * CH + c], pos);
      pos = fmaf(py, p.W_pos[1 * CH + c], pos);
      pos = fmaf(pz, p.W_pos[2 * CH + c], pos);
      xs[r][c] = h + pos;
    }
  }
  __syncthreads();

  // ---- q, k, v ----
#pragma unroll
  for (int i = 0; i < DH; ++i) acc[i] = p.bq[c0 + i];
  for (int k = 0; k < CH; ++k) fma16(xs[r][k], p.Wq + (size_t)k * CH + c0, acc);
#pragma unroll
  for (int i = 0; i < DH; ++i) qs[r][c0 + i] = acc[i] * 0.25f;  // 1/sqrt(Dh)

#pragma unroll
  for (int i = 0; i < DH; ++i) acc[i] = p.bk[c0 + i];
  for (int k = 0; k < CH; ++k) fma16(xs[r][k], p.Wk + (size_t)k * CH + c0, acc);
#pragma unroll
  for (int i = 0; i < DH; ++i) ksb[r][c0 + i] = acc[i];

#pragma unroll
  for (int i = 0; i < DH; ++i) acc[i] = p.bv[c0 + i];
  for (int k = 0; k < CH; ++k) fma16(xs[r][k], p.Wv + (size_t)k * CH + c0, acc);
#pragma unroll
  for (int i = 0; i < DH; ++i) vsb[r][c0 + i] = acc[i];
  __syncthreads();

  // ---- attention, head-serial ----
  float oacc[DH];
  for (int h = 0; h < NHEAD; ++h) {
    {
      int i  = t >> 3;
      int jb = (t & 7) * 4;
#pragma unroll
      for (int jj = 0; jj < 4; ++jj) {
        int j = jb + jj;
        float s = 0.f;
#pragma unroll
        for (int d = 0; d < DH; ++d)
          s = fmaf(qs[i][h * DH + d], ksb[j][h * DH + d], s);
        sb[i][j] = padf[j] ? -1e9f : s;
      }
    }
    __syncthreads();
    if (t < KNB) {
      float mx = -INFINITY;
#pragma unroll
      for (int j = 0; j < KNB; ++j) mx = fmaxf(mx, sb[t][j]);
      float sum = 0.f;
#pragma unroll
      for (int j = 0; j < KNB; ++j) sum += expf(sb[t][j] - mx);
      float inv = 1.0f / sum;
#pragma unroll
      for (int j = 0; j < KNB; ++j) sb[t][j] = expf(sb[t][j] - mx) * inv;
    }
    __syncthreads();
#pragma unroll
    for (int rep = 0; rep < 2; ++rep) {
      int e = t + rep * 256;
      int i = e >> 4, d = e & 15;
      float s = 0.f;
#pragma unroll
      for (int j = 0; j < KNB; ++j) s = fmaf(sb[i][j], vsb[j][h * DH + d], s);
      ob[i][d] = s;
    }
    __syncthreads();
    if (g == h) {
#pragma unroll
      for (int d = 0; d < DH; ++d) oacc[d] = ob[r][d];
    }
  }
  __syncthreads();
#pragma unroll
  for (int d = 0; d < DH; ++d) qs[r][c0 + d] = oacc[d];  // o -> qs
  __syncthreads();

  // ---- x = LN1(x + o @ Wo + bo) ----
#pragma unroll
  for (int i = 0; i < DH; ++i) acc[i] = p.bo[c0 + i];
  for (int k = 0; k < CH; ++k) fma16(qs[r][k], p.Wo + (size_t)k * CH + c0, acc);
#pragma unroll
  for (int i = 0; i < DH; ++i) acc[i] += xs[r][c0 + i];
  {
    float s = 0.f, sq = 0.f;
#pragma unroll
    for (int i = 0; i < DH; ++i) { s += acc[i]; sq += acc[i] * acc[i]; }
    redS[r][g] = s; redQ[r][g] = sq;
  }
  __syncthreads();
  if (t < KNB) {
    float s = 0.f, sq = 0.f;
#pragma unroll
    for (int gg = 0; gg < 8; ++gg) { s += redS[t][gg]; sq += redQ[t][gg]; }
    float mean = s * (1.0f / CH);
    float var  = fmaxf(sq * (1.0f / CH) - mean * mean, 0.f);
    mrow[t] = mean; irow[t] = rsqrtf(var + 1e-5f);
  }
  __syncthreads();
  {
    float mean = mrow[r], inv = irow[r];
#pragma unroll
    for (int i = 0; i < DH; ++i) {
      int c = c0 + i;
      xs[r][c] = (acc[i] - mean) * inv * p.ln1_g[c] + p.ln1_b[c];
    }
  }
  __syncthreads();

  // ---- FFN: x = LN2(x + relu(x@W1+b1)@W2 + b2), hidden in 4 chunks of 128 ----
  float x2[DH];
#pragma unroll
  for (int i = 0; i < DH; ++i) x2[i] = p.b2[c0 + i];
  for (int cb = 0; cb < 4; ++cb) {
    float hh[DH];
#pragma unroll
    for (int i = 0; i < DH; ++i) hh[i] = p.b1[cb * CH + c0 + i];
    for (int k = 0; k < CH; ++k)
      fma16(xs[r][k], p.W1 + (size_t)k * 4 * CH + cb * CH + c0, hh);
#pragma unroll
    for (int i = 0; i < DH; ++i) ksb[r][c0 + i] = fmaxf(hh[i], 0.f);
    __syncthreads();
    for (int k = 0; k < CH; ++k)
      fma16(ksb[r][k], p.W2 + (size_t)(cb * CH + k) * CH + c0, x2);
    __syncthreads();
  }
#pragma unroll
  for (int i = 0; i < DH; ++i) x2[i] += xs[r][c0 + i];
  {
    float s = 0.f, sq = 0.f;
#pragma unroll
    for (int i = 0; i < DH; ++i) { s += x2[i]; sq += x2[i] * x2[i]; }
    redS[r][g] = s; redQ[r][g] = sq;
  }
  __syncthreads();
  if (t < KNB) {
    float s = 0.f, sq = 0.f;
#pragma unroll
    for (int gg = 0; gg < 8; ++gg) { s += redS[t][gg]; sq += redQ[t][gg]; }
    float mean = s * (1.0f / CH);
    float var  = fmaxf(sq * (1.0f / CH) - mean * mean, 0.f);
    mrow[t] = mean; irow[t] = rsqrtf(var + 1e-5f);
  }
  __syncthreads();
  {
    float mean = mrow[r], inv = irow[r];
#pragma unroll
    for (int i = 0; i < DH; ++i) {
      int c = c0 + i;
      xs[r][c] = (x2[i] - mean) * inv * p.ln2_g[c] + p.ln2_b[c];
    }
  }
  __syncthreads();

  // ---- max-pool over K + LN(out) ----
  float pmax = -INFINITY;
  if (t < CH) {
#pragma unroll 4
    for (int rr = 0; rr < KNB; ++rr) pmax = fmaxf(pmax, xs[rr][t]);
    ((float*)sb)[t] = pmax;
  }
  __syncthreads();
  if (t == 0) {
    float s = 0.f, sq = 0.f;
    for (int c = 0; c < CH; ++c) { float v = ((float*)sb)[c]; s += v; sq += v * v; }
    float mean = s * (1.0f / CH);
    float var  = fmaxf(sq * (1.0f / CH) - mean * mean, 0.f);
    pstat[0] = mean; pstat[1] = rsqrtf(var + 1e-5f);
  }
  __syncthreads();
  if (t < CH) {
    float v = (pmax - pstat[0]) * pstat[1] * p.out_g[t] + p.out_b[t];
    p.out[(size_t)BATCH * M_CTR * 3 + (size_t)cm * CH + t] = v;
  }
}

// ---------------------------------------------------------------------------
extern "C" void kernel_launch(void* const* d_in, const int* in_sizes, int n_in,
                              void* d_out, int out_size, void* d_ws, size_t ws_size,
                              hipStream_t stream) {
  const float* xyz     = (const float*)d_in[0];
  const float* feats   = (const float*)d_in[1];
  const float* W_in    = (const float*)d_in[2];
  const float* b_in    = (const float*)d_in[3];
  const float* ln_in_g = (const float*)d_in[4];
  const float* ln_in_b = (const float*)d_in[5];
  const float* W_pos   = (const float*)d_in[6];
  const float* b_pos   = (const float*)d_in[7];
  const float* Wq      = (const float*)d_in[8];
  const float* bq      = (const float*)d_in[9];
  const float* Wk      = (const float*)d_in[10];
  const float* bk      = (const float*)d_in[11];
  const float* Wv      = (const float*)d_in[12];
  const float* bv      = (const float*)d_in[13];
  const float* Wo      = (const float*)d_in[14];
  const float* bo      = (const float*)d_in[15];
  const float* ln1_g   = (const float*)d_in[16];
  const float* ln1_b   = (const float*)d_in[17];
  const float* W1      = (const float*)d_in[18];
  const float* b1      = (const float*)d_in[19];
  const float* W2      = (const float*)d_in[20];
  const float* b2      = (const float*)d_in[21];
  const float* ln2_g   = (const float*)d_in[22];
  const float* ln2_b   = (const float*)d_in[23];
  const float* out_g   = (const float*)d_in[24];
  const float* out_b   = (const float*)d_in[25];
  float* out = (float*)d_out;

  int* wsCtr = (int*)d_ws;                 // B*M ints
  int* wsRaw = wsCtr + BATCH * M_CTR;      // B*M*K ints

  fps_kernel<<<BATCH, 1024, 0, stream>>>(xyz, wsCtr, out);
  ballq_kernel<<<(BATCH * M_CTR) / 4, 256, 0, stream>>>(xyz, wsCtr, wsRaw);

  SAParams p{xyz, feats, W_in, b_in, ln_in_g, ln_in_b, W_pos, b_pos,
             Wq, bq, Wk, bk, Wv, bv, Wo, bo, ln1_g, ln1_b,
             W1, b1, W2, b2, ln2_g, ln2_b, out_g, out_b,
             wsCtr, wsRaw, out};
  sa_kernel<<<BATCH * M_CTR, 256, 0, stream>>>(p);
}

// Round 2
// 6132.492 us; speedup vs baseline: 1.0899x; 1.0899x over previous
//
#include <hip/hip_runtime.h>
#include <math.h>

#define N_PTS 8192
#define BATCH 2
#define M_CTR 2048
#define KNB   32
#define CIN   64
#define CH    128
#define NHEAD 8
#define DH    16

// ---------------------------------------------------------------------------
// FPS v2: one block (256 thr, 4 waves) per batch. Each thread owns 32 points
// in REGISTERS (coords + running min-dist) -> zero LDS traffic in the hot
// loop except one uniform-broadcast read of the last winner's float4.
// One barrier per iteration via double-buffered per-wave candidates +
// redundant cross-wave reduce (deterministic f32 -> all waves agree).
// Exact f32 arithmetic (no FMA contraction) + first-index tie-break to match
// the numpy/JAX reference bitwise (discrete output!).
// ---------------------------------------------------------------------------
__global__ __launch_bounds__(256, 1) void fps_kernel(const float* __restrict__ xyz,
                                                     int* __restrict__ ctrIdx,
                                                     float* __restrict__ outCtr) {
  __shared__ float4 sxyz[N_PTS];      // 128 KB
  __shared__ float  candV[2][4];
  __shared__ int    candP[2][4];

  const int b = blockIdx.x;
  const int t = threadIdx.x;
  const int lane = t & 63;
  const int w = t >> 6;
  const float* xb = xyz + (size_t)b * N_PTS * 3;

  float px[32], py[32], pz[32], mind[32];
#pragma unroll
  for (int s = 0; s < 32; ++s) {
    int pt = t + s * 256;
    float x = xb[pt * 3 + 0];
    float y = xb[pt * 3 + 1];
    float z = xb[pt * 3 + 2];
    px[s] = x; py[s] = y; pz[s] = z;
    mind[s] = INFINITY;
    sxyz[pt] = make_float4(x, y, z, 0.f);
  }
  __syncthreads();

  int last = 0;
  for (int m = 0; m < M_CTR; ++m) {
    if (t == 0) {
      ctrIdx[b * M_CTR + m] = last;
      float4 c = sxyz[last];
      float* o = outCtr + (size_t)(b * M_CTR + m) * 3;
      o[0] = c.x; o[1] = c.y; o[2] = c.z;
    }
    float4 lp = sxyz[last];   // uniform broadcast read
    float bv = -INFINITY;
    int   bp = 0x7fffffff;
#pragma unroll
    for (int s = 0; s < 32; ++s) {
      float dx = __fsub_rn(px[s], lp.x);
      float dy = __fsub_rn(py[s], lp.y);
      float dz = __fsub_rn(pz[s], lp.z);
      float d2 = __fadd_rn(__fadd_rn(__fmul_rn(dx, dx), __fmul_rn(dy, dy)),
                           __fmul_rn(dz, dz));
      float mn = fminf(mind[s], d2);
      mind[s] = mn;
      if (mn > bv) { bv = mn; bp = t + s * 256; }  // ascending pt => strict > keeps first
    }
    // wave butterfly argmax (larger value wins; tie -> smaller index)
#pragma unroll
    for (int off = 1; off < 64; off <<= 1) {
      float ov = __shfl_xor(bv, off, 64);
      int   op = __shfl_xor(bp, off, 64);
      if (ov > bv || (ov == bv && op < bp)) { bv = ov; bp = op; }
    }
    const int buf = m & 1;
    if (lane == 0) { candV[buf][w] = bv; candP[buf][w] = bp; }
    __syncthreads();
    // redundant cross-wave reduce of the 4 candidates (all waves identical)
    float v2 = candV[buf][lane & 3];
    int   p2 = candP[buf][lane & 3];
#pragma unroll
    for (int off = 1; off < 4; off <<= 1) {
      float ov = __shfl_xor(v2, off, 64);
      int   op = __shfl_xor(p2, off, 64);
      if (ov > v2 || (ov == v2 && op < p2)) { v2 = ov; p2 = op; }
    }
    last = p2;
  }
}

// ---------------------------------------------------------------------------
// Ball query: one wave per center; first K=32 indices in ascending order with
// d2 < 0.25 (exact f32, no contraction). raw idx = -1 for pad slots.
// ---------------------------------------------------------------------------
__global__ __launch_bounds__(256) void ballq_kernel(const float* __restrict__ xyz,
                                                    const int* __restrict__ ctrIdx,
                                                    int* __restrict__ rawIdx) {
  const int cm   = blockIdx.x * 4 + (threadIdx.x >> 6);
  const int lane = threadIdx.x & 63;
  const int b    = cm >> 11;
  const float* xb = xyz + (size_t)b * N_PTS * 3;
  const int ci = ctrIdx[cm];
  const float cx = xb[ci * 3 + 0], cy = xb[ci * 3 + 1], cz = xb[ci * 3 + 2];
  int* out = rawIdx + (size_t)cm * KNB;
  int have = 0;
  for (int base = 0; base < N_PTS; base += 64) {
    int pt = base + lane;
    float dx = __fsub_rn(cx, xb[pt * 3 + 0]);
    float dy = __fsub_rn(cy, xb[pt * 3 + 1]);
    float dz = __fsub_rn(cz, xb[pt * 3 + 2]);
    float d2 = __fadd_rn(__fadd_rn(__fmul_rn(dx, dx), __fmul_rn(dy, dy)),
                         __fmul_rn(dz, dz));
    bool hit = d2 < 0.25f;
    unsigned long long mask = __ballot(hit);
    if (hit) {
      int rank = have + __popcll(mask & ((1ull << lane) - 1ull));
      if (rank < KNB) out[rank] = pt;
    }
    have += __popcll(mask);
    if (have >= KNB) break;
  }
  if (lane < KNB && lane >= have) out[lane] = -1;
}

// ---------------------------------------------------------------------------
// Fused per-center transformer. One block (256 thr) per center.
// Thread (t): row r = t&31 (neighbor slot), col group g = t>>5 owns cols
// [g*16, g*16+16). All [32][128] LDS tiles padded to 129 (bank conflicts).
// ---------------------------------------------------------------------------
struct SAParams {
  const float* xyz; const float* feats;
  const float* W_in; const float* b_in; const float* ln_in_g; const float* ln_in_b;
  const float* W_pos; const float* b_pos;
  const float* Wq; const float* bq; const float* Wk; const float* bk;
  const float* Wv; const float* bv; const float* Wo; const float* bo;
  const float* ln1_g; const float* ln1_b;
  const float* W1; const float* b1; const float* W2; const float* b2;
  const float* ln2_g; const float* ln2_b; const float* out_g; const float* out_b;
  const int* ctrIdx; const int* rawIdx;
  float* out;
};

__device__ __forceinline__ void fma16(float a, const float* __restrict__ w,
                                      float* acc) {
  const float4* w4 = (const float4*)w;
#pragma unroll
  for (int q4 = 0; q4 < 4; ++q4) {
    float4 wv = w4[q4];
    acc[q4 * 4 + 0] = fmaf(a, wv.x, acc[q4 * 4 + 0]);
    acc[q4 * 4 + 1] = fmaf(a, wv.y, acc[q4 * 4 + 1]);
    acc[q4 * 4 + 2] = fmaf(a, wv.z, acc[q4 * 4 + 2]);
    acc[q4 * 4 + 3] = fmaf(a, wv.w, acc[q4 * 4 + 3]);
  }
}

__global__ __launch_bounds__(256, 2) void sa_kernel(SAParams p) {
  __shared__ float xs[KNB][CH + 1];
  __shared__ float qs[KNB][CH + 1];
  __shared__ float ksb[KNB][CH + 1];
  __shared__ float vsb[KNB][CH + 1];
  __shared__ float sb[KNB][KNB + 1];
  __shared__ float ob[KNB][DH];
  __shared__ float redS[KNB][8];
  __shared__ float redQ[KNB][8];
  __shared__ float mrow[KNB];
  __shared__ float irow[KNB];
  __shared__ float pstat[2];
  __shared__ int   nidx[KNB];
  __shared__ int   padf[KNB];
  __shared__ float nx[KNB], ny[KNB], nz[KNB];

  const int t  = threadIdx.x;
  const int r  = t & 31;
  const int g  = t >> 5;
  const int c0 = g * DH;
  const int cm = blockIdx.x;
  const int b  = cm >> 11;

  if (t < KNB) {
    int raw = p.rawIdx[(size_t)cm * KNB + t];
    int ci  = p.ctrIdx[cm];
    int ni  = (raw < 0) ? ci : raw;
    nidx[t] = ni;
    padf[t] = (raw < 0) ? 1 : 0;
    const float* q = p.xyz + ((size_t)b * N_PTS + ni) * 3;
    nx[t] = q[0]; ny[t] = q[1]; nz[t] = q[2];
  }
  __syncthreads();

  // gather feats into qs rows (used as [32][64] scratch)
  for (int e = t; e < KNB * CIN; e += 256) {
    int rr = e >> 6, cc = e & 63;
    qs[rr][cc] = p.feats[((size_t)b * N_PTS + nidx[rr]) * CIN + cc];
  }
  __syncthreads();

  float acc[DH];
  // ---- input projection: h = feats @ W_in + b_in ----
#pragma unroll
  for (int i = 0; i < DH; ++i) acc[i] = p.b_in[c0 + i];
  for (int k = 0; k < CIN; ++k)
    fma16(qs[r][k], p.W_in + (size_t)k * CH + c0, acc);
  // LN(ln_in) + relu + pos-enc -> xs
  {
    float s = 0.f, sq = 0.f;
#pragma unroll
    for (int i = 0; i < DH; ++i) { s += acc[i]; sq += acc[i] * acc[i]; }
    redS[r][g] = s; redQ[r][g] = sq;
  }
  __syncthreads();
  if (t < KNB) {
    float s = 0.f, sq = 0.f;
#pragma unroll
    for (int gg = 0; gg < 8; ++gg) { s += redS[t][gg]; sq += redQ[t][gg]; }
    float mean = s * (1.0f / CH);
    float var  = fmaxf(sq * (1.0f / CH) - mean * mean, 0.f);
    mrow[t] = mean; irow[t] = rsqrtf(var + 1e-5f);
  }
  __syncthreads();
  {
    float mean = mrow[r], inv = irow[r];
    float pxv = nx[r], pyv = ny[r], pzv = nz[r];
#pragma unroll
    for (int i = 0; i < DH; ++i) {
      int c = c0 + i;
      float h = (acc[i] - mean) * inv * p.ln_in_g[c] + p.ln_in_b[c];
      h = fmaxf(h, 0.f);
      float pos = p.b_pos[c];
      pos = fmaf(pxv, p.W_pos[0 * CH + c], pos);
      pos = fmaf(pyv, p.W_pos[1 * CH + c], pos);
      pos = fmaf(pzv, p.W_pos[2 * CH + c], pos);
      xs[r][c] = h + pos;
    }
  }
  __syncthreads();

  // ---- q, k, v ----
#pragma unroll
  for (int i = 0; i < DH; ++i) acc[i] = p.bq[c0 + i];
  for (int k = 0; k < CH; ++k) fma16(xs[r][k], p.Wq + (size_t)k * CH + c0, acc);
#pragma unroll
  for (int i = 0; i < DH; ++i) qs[r][c0 + i] = acc[i] * 0.25f;  // 1/sqrt(Dh)

#pragma unroll
  for (int i = 0; i < DH; ++i) acc[i] = p.bk[c0 + i];
  for (int k = 0; k < CH; ++k) fma16(xs[r][k], p.Wk + (size_t)k * CH + c0, acc);
#pragma unroll
  for (int i = 0; i < DH; ++i) ksb[r][c0 + i] = acc[i];

#pragma unroll
  for (int i = 0; i < DH; ++i) acc[i] = p.bv[c0 + i];
  for (int k = 0; k < CH; ++k) fma16(xs[r][k], p.Wv + (size_t)k * CH + c0, acc);
#pragma unroll
  for (int i = 0; i < DH; ++i) vsb[r][c0 + i] = acc[i];
  __syncthreads();

  // ---- attention, head-serial ----
  float oacc[DH];
  for (int h = 0; h < NHEAD; ++h) {
    {
      int i  = t >> 3;
      int jb = (t & 7) * 4;
#pragma unroll
      for (int jj = 0; jj < 4; ++jj) {
        int j = jb + jj;
        float s = 0.f;
#pragma unroll
        for (int d = 0; d < DH; ++d)
          s = fmaf(qs[i][h * DH + d], ksb[j][h * DH + d], s);
        sb[i][j] = padf[j] ? -1e9f : s;
      }
    }
    __syncthreads();
    if (t < KNB) {
      float mx = -INFINITY;
#pragma unroll
      for (int j = 0; j < KNB; ++j) mx = fmaxf(mx, sb[t][j]);
      float sum = 0.f;
#pragma unroll
      for (int j = 0; j < KNB; ++j) sum += expf(sb[t][j] - mx);
      float inv = 1.0f / sum;
#pragma unroll
      for (int j = 0; j < KNB; ++j) sb[t][j] = expf(sb[t][j] - mx) * inv;
    }
    __syncthreads();
#pragma unroll
    for (int rep = 0; rep < 2; ++rep) {
      int e = t + rep * 256;
      int i = e >> 4, d = e & 15;
      float s = 0.f;
#pragma unroll
      for (int j = 0; j < KNB; ++j) s = fmaf(sb[i][j], vsb[j][h * DH + d], s);
      ob[i][d] = s;
    }
    __syncthreads();
    if (g == h) {
#pragma unroll
      for (int d = 0; d < DH; ++d) oacc[d] = ob[r][d];
    }
  }
  __syncthreads();
#pragma unroll
  for (int d = 0; d < DH; ++d) qs[r][c0 + d] = oacc[d];  // o -> qs
  __syncthreads();

  // ---- x = LN1(x + o @ Wo + bo) ----
#pragma unroll
  for (int i = 0; i < DH; ++i) acc[i] = p.bo[c0 + i];
  for (int k = 0; k < CH; ++k) fma16(qs[r][k], p.Wo + (size_t)k * CH + c0, acc);
#pragma unroll
  for (int i = 0; i < DH; ++i) acc[i] += xs[r][c0 + i];
  {
    float s = 0.f, sq = 0.f;
#pragma unroll
    for (int i = 0; i < DH; ++i) { s += acc[i]; sq += acc[i] * acc[i]; }
    redS[r][g] = s; redQ[r][g] = sq;
  }
  __syncthreads();
  if (t < KNB) {
    float s = 0.f, sq = 0.f;
#pragma unroll
    for (int gg = 0; gg < 8; ++gg) { s += redS[t][gg]; sq += redQ[t][gg]; }
    float mean = s * (1.0f / CH);
    float var  = fmaxf(sq * (1.0f / CH) - mean * mean, 0.f);
    mrow[t] = mean; irow[t] = rsqrtf(var + 1e-5f);
  }
  __syncthreads();
  {
    float mean = mrow[r], inv = irow[r];
#pragma unroll
    for (int i = 0; i < DH; ++i) {
      int c = c0 + i;
      xs[r][c] = (acc[i] - mean) * inv * p.ln1_g[c] + p.ln1_b[c];
    }
  }
  __syncthreads();

  // ---- FFN: x = LN2(x + relu(x@W1+b1)@W2 + b2), hidden in 4 chunks of 128 ----
  float x2[DH];
#pragma unroll
  for (int i = 0; i < DH; ++i) x2[i] = p.b2[c0 + i];
  for (int cb = 0; cb < 4; ++cb) {
    float hh[DH];
#pragma unroll
    for (int i = 0; i < DH; ++i) hh[i] = p.b1[cb * CH + c0 + i];
    for (int k = 0; k < CH; ++k)
      fma16(xs[r][k], p.W1 + (size_t)k * 4 * CH + cb * CH + c0, hh);
#pragma unroll
    for (int i = 0; i < DH; ++i) ksb[r][c0 + i] = fmaxf(hh[i], 0.f);
    __syncthreads();
    for (int k = 0; k < CH; ++k)
      fma16(ksb[r][k], p.W2 + (size_t)(cb * CH + k) * CH + c0, x2);
    __syncthreads();
  }
#pragma unroll
  for (int i = 0; i < DH; ++i) x2[i] += xs[r][c0 + i];
  {
    float s = 0.f, sq = 0.f;
#pragma unroll
    for (int i = 0; i < DH; ++i) { s += x2[i]; sq += x2[i] * x2[i]; }
    redS[r][g] = s; redQ[r][g] = sq;
  }
  __syncthreads();
  if (t < KNB) {
    float s = 0.f, sq = 0.f;
#pragma unroll
    for (int gg = 0; gg < 8; ++gg) { s += redS[t][gg]; sq += redQ[t][gg]; }
    float mean = s * (1.0f / CH);
    float var  = fmaxf(sq * (1.0f / CH) - mean * mean, 0.f);
    mrow[t] = mean; irow[t] = rsqrtf(var + 1e-5f);
  }
  __syncthreads();
  {
    float mean = mrow[r], inv = irow[r];
#pragma unroll
    for (int i = 0; i < DH; ++i) {
      int c = c0 + i;
      xs[r][c] = (x2[i] - mean) * inv * p.ln2_g[c] + p.ln2_b[c];
    }
  }
  __syncthreads();

  // ---- max-pool over K + LN(out) ----
  float pmax = -INFINITY;
  if (t < CH) {
#pragma unroll 4
    for (int rr = 0; rr < KNB; ++rr) pmax = fmaxf(pmax, xs[rr][t]);
    ((float*)sb)[t] = pmax;
  }
  __syncthreads();
  if (t == 0) {
    float s = 0.f, sq = 0.f;
    for (int c = 0; c < CH; ++c) { float v = ((float*)sb)[c]; s += v; sq += v * v; }
    float mean = s * (1.0f / CH);
    float var  = fmaxf(sq * (1.0f / CH) - mean * mean, 0.f);
    pstat[0] = mean; pstat[1] = rsqrtf(var + 1e-5f);
  }
  __syncthreads();
  if (t < CH) {
    float v = (pmax - pstat[0]) * pstat[1] * p.out_g[t] + p.out_b[t];
    p.out[(size_t)BATCH * M_CTR * 3 + (size_t)cm * CH + t] = v;
  }
}

// ---------------------------------------------------------------------------
extern "C" void kernel_launch(void* const* d_in, const int* in_sizes, int n_in,
                              void* d_out, int out_size, void* d_ws, size_t ws_size,
                              hipStream_t stream) {
  const float* xyz     = (const float*)d_in[0];
  const float* feats   = (const float*)d_in[1];
  const float* W_in    = (const float*)d_in[2];
  const float* b_in    = (const float*)d_in[3];
  const float* ln_in_g = (const float*)d_in[4];
  const float* ln_in_b = (const float*)d_in[5];
  const float* W_pos   = (const float*)d_in[6];
  const float* b_pos   = (const float*)d_in[7];
  const float* Wq      = (const float*)d_in[8];
  const float* bq      = (const float*)d_in[9];
  const float* Wk      = (const float*)d_in[10];
  const float* bk      = (const float*)d_in[11];
  const float* Wv      = (const float*)d_in[12];
  const float* bv      = (const float*)d_in[13];
  const float* Wo      = (const float*)d_in[14];
  const float* bo      = (const float*)d_in[15];
  const float* ln1_g   = (const float*)d_in[16];
  const float* ln1_b   = (const float*)d_in[17];
  const float* W1      = (const float*)d_in[18];
  const float* b1      = (const float*)d_in[19];
  const float* W2      = (const float*)d_in[20];
  const float* b2      = (const float*)d_in[21];
  const float* ln2_g   = (const float*)d_in[22];
  const float* ln2_b   = (const float*)d_in[23];
  const float* out_g   = (const float*)d_in[24];
  const float* out_b   = (const float*)d_in[25];
  float* out = (float*)d_out;

  int* wsCtr = (int*)d_ws;                 // B*M ints
  int* wsRaw = wsCtr + BATCH * M_CTR;      // B*M*K ints

  fps_kernel<<<BATCH, 256, 0, stream>>>(xyz, wsCtr, out);
  ballq_kernel<<<(BATCH * M_CTR) / 4, 256, 0, stream>>>(xyz, wsCtr, wsRaw);

  SAParams p{xyz, feats, W_in, b_in, ln_in_g, ln_in_b, W_pos, b_pos,
             Wq, bq, Wk, bk, Wv, bv, Wo, bo, ln1_g, ln1_b,
             W1, b1, W2, b2, ln2_g, ln2_b, out_g, out_b,
             wsCtr, wsRaw, out};
  sa_kernel<<<BATCH * M_CTR, 256, 0, stream>>>(p);
}

// Round 3
// 3502.810 us; speedup vs baseline: 1.9081x; 1.7507x over previous
//
#include <hip/hip_runtime.h>
#include <math.h>

#define N_PTS 8192
#define BATCH 2
#define M_CTR 2048
#define KNB   32
#define CIN   64
#define CH    128
#define NHEAD 8
#define DH    16
#define TP    132   // padded LDS tile stride (floats): 16B-aligned rows, banks spread

// ---------------------------------------------------------------------------
// FPS v3: one block (512 thr, 8 waves) per batch. Coords + min-dist in regs
// (16 pts/thread). Argmax via packed u64 key (bits(d2)<<32)|~idx  -> total
// order == (value desc, index asc): EXACT numpy first-index argmax in any
// reduction order. Per-thread tree (depth 5), wave butterfly, 1 barrier/iter.
// Distances use exact f32 ops (no FMA contraction) matching the reference.
// ---------------------------------------------------------------------------
__global__ __launch_bounds__(512, 1) void fps_kernel(const float* __restrict__ xyz,
                                                     int* __restrict__ ctrIdx,
                                                     float* __restrict__ outCtr) {
  __shared__ float4 sxyz[N_PTS];                    // 128 KB
  __shared__ int    cidx[M_CTR];                    // 8 KB
  __shared__ unsigned long long candK[2][8];

  const int b = blockIdx.x;
  const int t = threadIdx.x;
  const int lane = t & 63;
  const int w = t >> 6;
  const float* xb = xyz + (size_t)b * N_PTS * 3;

  float px[16], py[16], pz[16], mind[16];
#pragma unroll
  for (int s = 0; s < 16; ++s) {
    int pt = t + s * 512;
    float x = xb[pt * 3 + 0];
    float y = xb[pt * 3 + 1];
    float z = xb[pt * 3 + 2];
    px[s] = x; py[s] = y; pz[s] = z;
    mind[s] = INFINITY;
    sxyz[pt] = make_float4(x, y, z, 0.f);
  }
  __syncthreads();

  int last = 0;
  for (int m = 0; m < M_CTR; ++m) {
    if (t == 0) cidx[m] = last;
    float4 lp = sxyz[last];                          // uniform broadcast
    unsigned long long key[16];
#pragma unroll
    for (int s = 0; s < 16; ++s) {
      float dx = __fsub_rn(px[s], lp.x);
      float dy = __fsub_rn(py[s], lp.y);
      float dz = __fsub_rn(pz[s], lp.z);
      float d2 = __fadd_rn(__fadd_rn(__fmul_rn(dx, dx), __fmul_rn(dy, dy)),
                           __fmul_rn(dz, dz));
      float mn = fminf(mind[s], d2);
      mind[s] = mn;
      unsigned lo = ~(unsigned)(t + s * 512);
      key[s] = ((unsigned long long)__float_as_uint(mn) << 32) | lo;
    }
    // per-thread tree max (depth 5)
#pragma unroll
    for (int i = 0; i < 8; ++i) key[i] = key[i] > key[i + 8] ? key[i] : key[i + 8];
#pragma unroll
    for (int i = 0; i < 4; ++i) key[i] = key[i] > key[i + 4] ? key[i] : key[i + 4];
#pragma unroll
    for (int i = 0; i < 2; ++i) key[i] = key[i] > key[i + 2] ? key[i] : key[i + 2];
    unsigned long long k0 = key[0] > key[1] ? key[0] : key[1];
    // wave butterfly
#pragma unroll
    for (int off = 1; off < 64; off <<= 1) {
      unsigned long long o = __shfl_xor(k0, off, 64);
      k0 = o > k0 ? o : k0;
    }
    const int buf = m & 1;
    if (lane == 0) candK[buf][w] = k0;
    __syncthreads();
    unsigned long long best = candK[buf][0];
#pragma unroll
    for (int i = 1; i < 8; ++i) {
      unsigned long long c = candK[buf][i];
      best = c > best ? c : best;
    }
    last = (int)(~(unsigned)best);
  }
  __syncthreads();
  for (int m = t; m < M_CTR; m += 512) {
    int ci = cidx[m];
    ctrIdx[b * M_CTR + m] = ci;
    float4 c = sxyz[ci];
    float* o = outCtr + (size_t)(b * M_CTR + m) * 3;
    o[0] = c.x; o[1] = c.y; o[2] = c.z;
  }
}

// ---------------------------------------------------------------------------
// Ball query: one wave per center; first K=32 ascending indices with d2<0.25
// (exact f32, no contraction). raw idx = -1 for pad slots.
// ---------------------------------------------------------------------------
__global__ __launch_bounds__(256) void ballq_kernel(const float* __restrict__ xyz,
                                                    const int* __restrict__ ctrIdx,
                                                    int* __restrict__ rawIdx) {
  const int cm   = blockIdx.x * 4 + (threadIdx.x >> 6);
  const int lane = threadIdx.x & 63;
  const int b    = cm >> 11;
  const float* xb = xyz + (size_t)b * N_PTS * 3;
  const int ci = ctrIdx[cm];
  const float cx = xb[ci * 3 + 0], cy = xb[ci * 3 + 1], cz = xb[ci * 3 + 2];
  int* out = rawIdx + (size_t)cm * KNB;
  int have = 0;
  for (int base = 0; base < N_PTS; base += 64) {
    int pt = base + lane;
    float dx = __fsub_rn(cx, xb[pt * 3 + 0]);
    float dy = __fsub_rn(cy, xb[pt * 3 + 1]);
    float dz = __fsub_rn(cz, xb[pt * 3 + 2]);
    float d2 = __fadd_rn(__fadd_rn(__fmul_rn(dx, dx), __fmul_rn(dy, dy)),
                         __fmul_rn(dz, dz));
    bool hit = d2 < 0.25f;
    unsigned long long mask = __ballot(hit);
    if (hit) {
      int rank = have + __popcll(mask & ((1ull << lane) - 1ull));
      if (rank < KNB) out[rank] = pt;
    }
    have += __popcll(mask);
    if (have >= KNB) break;
  }
  if (lane < KNB && lane >= have) out[lane] = -1;
}

// ---------------------------------------------------------------------------
// Fused per-center transformer v2. One block (256 thr) per center.
// Matmuls: thread = (colgroup cg: 8 cols, rowgroup: 4 rows, k-half kk).
//   lane bits: cg=lane&15, rgLow=(lane>>4)&1, kk=(lane>>5)&1; r0=w*8+rgLow*4.
//   k-split reduced via __shfl_xor(.,32) (same wave). LN stats via in-wave
//   butterfly over cg lanes (xor 1,2,4,8). Attention: thread=(head,row),
//   scores+softmax+PV fully in registers, zero barriers.
// ---------------------------------------------------------------------------
struct SAParams {
  const float* xyz; const float* feats;
  const float* W_in; const float* b_in; const float* ln_in_g; const float* ln_in_b;
  const float* W_pos; const float* b_pos;
  const float* Wq; const float* bq; const float* Wk; const float* bk;
  const float* Wv; const float* bv; const float* Wo; const float* bo;
  const float* ln1_g; const float* ln1_b;
  const float* W1; const float* b1; const float* W2; const float* b2;
  const float* ln2_g; const float* ln2_b; const float* out_g; const float* out_b;
  const int* ctrIdx; const int* rawIdx;
  float* out;
};

// acc[4 rows][8 cols] += src[r0..r0+4][k0..k0+KH] * W[k][c0..c0+8]
template<int KH, int RS>
__device__ __forceinline__ void mm_rb(const float* __restrict__ src, int r0, int k0,
                                      const float* __restrict__ W, int ldw, int c0,
                                      float (&acc)[4][8]) {
#pragma unroll 2
  for (int kb = 0; kb < KH; kb += 4) {
    const int k = k0 + kb;
    float4 xv0 = *(const float4*)(src + (r0 + 0) * RS + k);
    float4 xv1 = *(const float4*)(src + (r0 + 1) * RS + k);
    float4 xv2 = *(const float4*)(src + (r0 + 2) * RS + k);
    float4 xv3 = *(const float4*)(src + (r0 + 3) * RS + k);
    const float* wr = W + (size_t)k * ldw + c0;
#pragma unroll
    for (int u = 0; u < 4; ++u) {
      float4 wa = *(const float4*)(wr + (size_t)u * ldw);
      float4 wb = *(const float4*)(wr + (size_t)u * ldw + 4);
      float xk0 = (&xv0.x)[u], xk1 = (&xv1.x)[u];
      float xk2 = (&xv2.x)[u], xk3 = (&xv3.x)[u];
#pragma unroll
      for (int j = 0; j < 4; ++j) {
        float wav = (&wa.x)[j], wbv = (&wb.x)[j];
        acc[0][j]     = fmaf(xk0, wav, acc[0][j]);
        acc[1][j]     = fmaf(xk1, wav, acc[1][j]);
        acc[2][j]     = fmaf(xk2, wav, acc[2][j]);
        acc[3][j]     = fmaf(xk3, wav, acc[3][j]);
        acc[0][4 + j] = fmaf(xk0, wbv, acc[0][4 + j]);
        acc[1][4 + j] = fmaf(xk1, wbv, acc[1][4 + j]);
        acc[2][4 + j] = fmaf(xk2, wbv, acc[2][4 + j]);
        acc[3][4 + j] = fmaf(xk3, wbv, acc[3][4 + j]);
      }
    }
  }
}

__device__ __forceinline__ void xchg_add(float (&acc)[4][8]) {
#pragma unroll
  for (int i = 0; i < 4; ++i)
#pragma unroll
    for (int j = 0; j < 8; ++j)
      acc[i][j] += __shfl_xor(acc[i][j], 32, 64);
}

__device__ __forceinline__ void add_bias(float (&acc)[4][8], const float* bptr, int c0) {
  float4 ba = *(const float4*)(bptr + c0);
  float4 bb = *(const float4*)(bptr + c0 + 4);
#pragma unroll
  for (int i = 0; i < 4; ++i)
#pragma unroll
    for (int j = 0; j < 4; ++j) {
      acc[i][j]     += (&ba.x)[j];
      acc[i][4 + j] += (&bb.x)[j];
    }
}

// mean/inv-std per row (butterfly over cg lanes: bits 0..3)
__device__ __forceinline__ void row_stats(const float (&acc)[4][8],
                                          float (&mean)[4], float (&inv)[4]) {
#pragma unroll
  for (int i = 0; i < 4; ++i) {
    float s = 0.f, sq = 0.f;
#pragma unroll
    for (int j = 0; j < 8; ++j) { s += acc[i][j]; sq += acc[i][j] * acc[i][j]; }
#pragma unroll
    for (int off = 1; off < 16; off <<= 1) {
      s  += __shfl_xor(s,  off, 64);
      sq += __shfl_xor(sq, off, 64);
    }
    float mn = s * (1.0f / CH);
    float var = fmaxf(sq * (1.0f / CH) - mn * mn, 0.f);
    mean[i] = mn;
    inv[i]  = rsqrtf(var + 1e-5f);
  }
}

__global__ __launch_bounds__(256, 2) void sa_kernel(SAParams p) {
  __shared__ float smem[4 * KNB * TP];      // xs | qs | ksb | vsb
  __shared__ int   nidx[KNB];
  __shared__ int   padf[KNB];
  __shared__ float nxs[KNB], nys[KNB], nzs[KNB];
  __shared__ float psum[2][2];

  float* const xsb  = smem;
  float* const qsb  = smem + KNB * TP;
  float* const ksbb = smem + 2 * KNB * TP;
  float* const vsbb = smem + 3 * KNB * TP;

  const int t    = threadIdx.x;
  const int lane = t & 63;
  const int w    = t >> 6;
  const int cg   = lane & 15;
  const int rgL  = (lane >> 4) & 1;
  const int kk   = (lane >> 5) & 1;
  const int r0   = w * 8 + rgL * 4;
  const int c0   = cg * 8;
  const int cm   = blockIdx.x;
  const int b    = cm >> 11;

  if (t < KNB) {
    int raw = p.rawIdx[(size_t)cm * KNB + t];
    int ci  = p.ctrIdx[cm];
    int ni  = (raw < 0) ? ci : raw;
    nidx[t] = ni;
    padf[t] = (raw < 0) ? 1 : 0;
    const float* q = p.xyz + ((size_t)b * N_PTS + ni) * 3;
    nxs[t] = q[0]; nys[t] = q[1]; nzs[t] = q[2];
  }
  __syncthreads();

  // ---- gather feats into fs (= qs region) as [32][68] ----
  float* const fsb = qsb;                 // stride 68
  for (int e = t; e < KNB * CIN; e += 256) {
    int rr = e >> 6, cc = e & 63;
    fsb[rr * 68 + cc] = p.feats[((size_t)b * N_PTS + nidx[rr]) * CIN + cc];
  }
  __syncthreads();

  // ---- in-proj + LN + relu + posenc -> xs ----
  {
    float acc[4][8] = {};
    mm_rb<32, 68>(fsb, r0, kk * 32, p.W_in, CH, c0, acc);
    xchg_add(acc);
    add_bias(acc, p.b_in, c0);
    float mean[4], inv[4];
    row_stats(acc, mean, inv);
    float4 g  = *(const float4*)(p.ln_in_g + c0 + kk * 4);
    float4 bt = *(const float4*)(p.ln_in_b + c0 + kk * 4);
    float4 w0 = *(const float4*)(p.W_pos + 0 * CH + c0 + kk * 4);
    float4 w1 = *(const float4*)(p.W_pos + 1 * CH + c0 + kk * 4);
    float4 w2 = *(const float4*)(p.W_pos + 2 * CH + c0 + kk * 4);
    float4 bp = *(const float4*)(p.b_pos + c0 + kk * 4);
#pragma unroll
    for (int i = 0; i < 4; ++i) {
      int r = r0 + i;
      float x = nxs[r], y = nys[r], z = nzs[r];
      float4 o;
#pragma unroll
      for (int j = 0; j < 4; ++j) {
        float hv = (acc[i][kk * 4 + j] - mean[i]) * inv[i] * (&g.x)[j] + (&bt.x)[j];
        hv = fmaxf(hv, 0.f);
        float pos = fmaf(x, (&w0.x)[j], fmaf(y, (&w1.x)[j],
                     fmaf(z, (&w2.x)[j], (&bp.x)[j])));
        (&o.x)[j] = hv + pos;
      }
      *(float4*)(xsb + r * TP + c0 + kk * 4) = o;
    }
  }
  __syncthreads();

  // ---- q, k, v (q pre-scaled by 1/sqrt(Dh)=0.25 — exact pow2) ----
  {
    float acc[4][8] = {};
    mm_rb<64, TP>(xsb, r0, kk * 64, p.Wq, CH, c0, acc);
    xchg_add(acc);
    add_bias(acc, p.bq, c0);
#pragma unroll
    for (int i = 0; i < 4; ++i) {
      float4 o;
#pragma unroll
      for (int j = 0; j < 4; ++j) (&o.x)[j] = acc[i][kk * 4 + j] * 0.25f;
      *(float4*)(qsb + (r0 + i) * TP + c0 + kk * 4) = o;
    }
  }
  {
    float acc[4][8] = {};
    mm_rb<64, TP>(xsb, r0, kk * 64, p.Wk, CH, c0, acc);
    xchg_add(acc);
    add_bias(acc, p.bk, c0);
#pragma unroll
    for (int i = 0; i < 4; ++i) {
      float4 o;
#pragma unroll
      for (int j = 0; j < 4; ++j) (&o.x)[j] = acc[i][kk * 4 + j];
      *(float4*)(ksbb + (r0 + i) * TP + c0 + kk * 4) = o;
    }
  }
  {
    float acc[4][8] = {};
    mm_rb<64, TP>(xsb, r0, kk * 64, p.Wv, CH, c0, acc);
    xchg_add(acc);
    add_bias(acc, p.bv, c0);
#pragma unroll
    for (int i = 0; i < 4; ++i) {
      float4 o;
#pragma unroll
      for (int j = 0; j < 4; ++j) (&o.x)[j] = acc[i][kk * 4 + j];
      *(float4*)(vsbb + (r0 + i) * TP + c0 + kk * 4) = o;
    }
  }
  __syncthreads();

  // ---- attention: thread = (head h, row i); all in registers ----
  {
    const int h  = t >> 5;
    const int qi = t & 31;
    float qv[16];
#pragma unroll
    for (int c = 0; c < 4; ++c)
      *(float4*)&qv[c * 4] = *(const float4*)(qsb + qi * TP + h * DH + c * 4);
    float sc[KNB];
#pragma unroll
    for (int j = 0; j < KNB; ++j) {
      float d = 0.f;
#pragma unroll
      for (int c = 0; c < 4; ++c) {
        float4 kv = *(const float4*)(ksbb + j * TP + h * DH + c * 4);
#pragma unroll
        for (int e = 0; e < 4; ++e) d = fmaf(qv[c * 4 + e], (&kv.x)[e], d);
      }
      sc[j] = padf[j] ? -1e9f : d;
    }
    float mx = -INFINITY;
#pragma unroll
    for (int j = 0; j < KNB; ++j) mx = fmaxf(mx, sc[j]);
    float se = 0.f;
#pragma unroll
    for (int j = 0; j < KNB; ++j) { sc[j] = expf(sc[j] - mx); se += sc[j]; }
    float isum = 1.0f / se;
    float ov[16] = {};
#pragma unroll
    for (int j = 0; j < KNB; ++j) {
      float pj = sc[j];
#pragma unroll
      for (int c = 0; c < 4; ++c) {
        float4 vv = *(const float4*)(vsbb + j * TP + h * DH + c * 4);
#pragma unroll
        for (int e = 0; e < 4; ++e)
          ov[c * 4 + e] = fmaf(pj, (&vv.x)[e], ov[c * 4 + e]);
      }
    }
#pragma unroll
    for (int c = 0; c < 4; ++c) {
      float4 o;
#pragma unroll
      for (int e = 0; e < 4; ++e) (&o.x)[e] = ov[c * 4 + e] * isum;
      *(float4*)(qsb + qi * TP + h * DH + c * 4) = o;   // own slice; q already read
    }
  }
  __syncthreads();

  // ---- x = LN1(x + o @ Wo + bo) ----
  {
    float acc[4][8] = {};
    mm_rb<64, TP>(qsb, r0, kk * 64, p.Wo, CH, c0, acc);
    xchg_add(acc);
    add_bias(acc, p.bo, c0);
#pragma unroll
    for (int i = 0; i < 4; ++i) {
      float4 ra = *(const float4*)(xsb + (r0 + i) * TP + c0);
      float4 rb = *(const float4*)(xsb + (r0 + i) * TP + c0 + 4);
#pragma unroll
      for (int j = 0; j < 4; ++j) { acc[i][j] += (&ra.x)[j]; acc[i][4 + j] += (&rb.x)[j]; }
    }
    float mean[4], inv[4];
    row_stats(acc, mean, inv);
    float4 g  = *(const float4*)(p.ln1_g + c0 + kk * 4);
    float4 bt = *(const float4*)(p.ln1_b + c0 + kk * 4);
#pragma unroll
    for (int i = 0; i < 4; ++i) {
      float4 o;
#pragma unroll
      for (int j = 0; j < 4; ++j)
        (&o.x)[j] = (acc[i][kk * 4 + j] - mean[i]) * inv[i] * (&g.x)[j] + (&bt.x)[j];
      *(float4*)(xsb + (r0 + i) * TP + c0 + kk * 4) = o;
    }
  }
  __syncthreads();

  // ---- FFN: x = LN2(x + relu(x@W1+b1)@W2 + b2), hidden in 4 chunks of 128 ----
  {
    float acc2[4][8] = {};
    for (int cb = 0; cb < 4; ++cb) {
      float acch[4][8] = {};
      mm_rb<64, TP>(xsb, r0, kk * 64, p.W1 + cb * CH, 4 * CH, c0, acch);
      xchg_add(acch);
      add_bias(acch, p.b1 + cb * CH, c0);
#pragma unroll
      for (int i = 0; i < 4; ++i) {
        float4 o;
#pragma unroll
        for (int j = 0; j < 4; ++j) (&o.x)[j] = fmaxf(acch[i][kk * 4 + j], 0.f);
        *(float4*)(ksbb + (r0 + i) * TP + c0 + kk * 4) = o;
      }
      __syncthreads();
      mm_rb<64, TP>(ksbb, r0, kk * 64, p.W2 + (size_t)cb * CH * CH, CH, c0, acc2);
      __syncthreads();
    }
    xchg_add(acc2);
    add_bias(acc2, p.b2, c0);
#pragma unroll
    for (int i = 0; i < 4; ++i) {
      float4 ra = *(const float4*)(xsb + (r0 + i) * TP + c0);
      float4 rb = *(const float4*)(xsb + (r0 + i) * TP + c0 + 4);
#pragma unroll
      for (int j = 0; j < 4; ++j) { acc2[i][j] += (&ra.x)[j]; acc2[i][4 + j] += (&rb.x)[j]; }
    }
    float mean[4], inv[4];
    row_stats(acc2, mean, inv);
    float4 g  = *(const float4*)(p.ln2_g + c0 + kk * 4);
    float4 bt = *(const float4*)(p.ln2_b + c0 + kk * 4);
#pragma unroll
    for (int i = 0; i < 4; ++i) {
      float4 o;
#pragma unroll
      for (int j = 0; j < 4; ++j)
        (&o.x)[j] = (acc2[i][kk * 4 + j] - mean[i]) * inv[i] * (&g.x)[j] + (&bt.x)[j];
      *(float4*)(xsb + (r0 + i) * TP + c0 + kk * 4) = o;
    }
  }
  __syncthreads();

  // ---- max-pool over K + LN(out) ----
  float pmax = -INFINITY;
  if (t < CH) {
#pragma unroll 8
    for (int rr = 0; rr < KNB; ++rr) pmax = fmaxf(pmax, xsb[rr * TP + t]);
    float s = pmax, sq = pmax * pmax;
#pragma unroll
    for (int off = 1; off < 64; off <<= 1) {
      s  += __shfl_xor(s,  off, 64);
      sq += __shfl_xor(sq, off, 64);
    }
    if (lane == 0) { psum[w][0] = s; psum[w][1] = sq; }
  }
  __syncthreads();
  if (t < CH) {
    float s = psum[0][0] + psum[1][0];
    float sq = psum[0][1] + psum[1][1];
    float mean = s * (1.0f / CH);
    float var = fmaxf(sq * (1.0f / CH) - mean * mean, 0.f);
    float inv = rsqrtf(var + 1e-5f);
    float v = (pmax - mean) * inv * p.out_g[t] + p.out_b[t];
    p.out[(size_t)BATCH * M_CTR * 3 + (size_t)cm * CH + t] = v;
  }
}

// ---------------------------------------------------------------------------
extern "C" void kernel_launch(void* const* d_in, const int* in_sizes, int n_in,
                              void* d_out, int out_size, void* d_ws, size_t ws_size,
                              hipStream_t stream) {
  const float* xyz     = (const float*)d_in[0];
  const float* feats   = (const float*)d_in[1];
  const float* W_in    = (const float*)d_in[2];
  const float* b_in    = (const float*)d_in[3];
  const float* ln_in_g = (const float*)d_in[4];
  const float* ln_in_b = (const float*)d_in[5];
  const float* W_pos   = (const float*)d_in[6];
  const float* b_pos   = (const float*)d_in[7];
  const float* Wq      = (const float*)d_in[8];
  const float* bq      = (const float*)d_in[9];
  const float* Wk      = (const float*)d_in[10];
  const float* bk      = (const float*)d_in[11];
  const float* Wv      = (const float*)d_in[12];
  const float* bv      = (const float*)d_in[13];
  const float* Wo      = (const float*)d_in[14];
  const float* bo      = (const float*)d_in[15];
  const float* ln1_g   = (const float*)d_in[16];
  const float* ln1_b   = (const float*)d_in[17];
  const float* W1      = (const float*)d_in[18];
  const float* b1      = (const float*)d_in[19];
  const float* W2      = (const float*)d_in[20];
  const float* b2      = (const float*)d_in[21];
  const float* ln2_g   = (const float*)d_in[22];
  const float* ln2_b   = (const float*)d_in[23];
  const float* out_g   = (const float*)d_in[24];
  const float* out_b   = (const float*)d_in[25];
  float* out = (float*)d_out;

  int* wsCtr = (int*)d_ws;                 // B*M ints
  int* wsRaw = wsCtr + BATCH * M_CTR;      // B*M*K ints

  fps_kernel<<<BATCH, 512, 0, stream>>>(xyz, wsCtr, out);
  ballq_kernel<<<(BATCH * M_CTR) / 4, 256, 0, stream>>>(xyz, wsCtr, wsRaw);

  SAParams p{xyz, feats, W_in, b_in, ln_in_g, ln_in_b, W_pos, b_pos,
             Wq, bq, Wk, bk, Wv, bv, Wo, bo, ln1_g, ln1_b,
             W1, b1, W2, b2, ln2_g, ln2_b, out_g, out_b,
             wsCtr, wsRaw, out};
  sa_kernel<<<BATCH * M_CTR, 256, 0, stream>>>(p);
}

// Round 5
// 3318.452 us; speedup vs baseline: 2.0141x; 1.0556x over previous
//
#include <hip/hip_runtime.h>
#include <math.h>

#define N_PTS 8192
#define BATCH 2
#define M_CTR 2048
#define KNB   32
#define CIN   64
#define CH    128
#define NHEAD 8
#define DH    16
#define TP    132   // padded LDS tile stride (floats): 16B-aligned rows

// ---------------------------------------------------------------------------
// FPS v5: 512 thr/block, 16 pts/thread in registers. Argmax via packed u64
// key (bits(d2)<<32)|~idx == (value desc, index asc) total order -> EXACT
// numpy first-index argmax in any reduction order. Wave reduce: 4 DPP stages
// on the VALU pipe — xor1, xor2 (quad_perm), xor7 (row_half_mirror), xor15
// (row_mirror) — a complete all-reduce over each row of 16 (verified lattice:
// after quad stages lane has M[q]; xor7 partner q^1 -> half-row max; xor15
// partner q^3 holds {q^2,q^3} -> full row) + ds_swizzle xor16 + shfl xor32.
// One barrier/iter (double-buffered candidates). Distances: exact f32 ops
// (no FMA contraction), matching the reference bitwise.
// ---------------------------------------------------------------------------
template<int CTRL>
__device__ __forceinline__ unsigned long long dpp_max_u64(unsigned long long k) {
  int lo = (int)(unsigned)k;
  int hi = (int)(k >> 32);
  int lo2 = __builtin_amdgcn_update_dpp(0, lo, CTRL, 0xF, 0xF, true);
  int hi2 = __builtin_amdgcn_update_dpp(0, hi, CTRL, 0xF, 0xF, true);
  unsigned long long o = ((unsigned long long)(unsigned)hi2 << 32) | (unsigned)lo2;
  return o > k ? o : k;
}

__device__ __forceinline__ unsigned long long swz16_max_u64(unsigned long long k) {
  int lo = (int)(unsigned)k;
  int hi = (int)(k >> 32);
  int lo2 = __builtin_amdgcn_ds_swizzle(lo, 0x401F);   // xor 16
  int hi2 = __builtin_amdgcn_ds_swizzle(hi, 0x401F);
  unsigned long long o = ((unsigned long long)(unsigned)hi2 << 32) | (unsigned)lo2;
  return o > k ? o : k;
}

__device__ __forceinline__ unsigned long long maxu64(unsigned long long a,
                                                     unsigned long long b) {
  return a > b ? a : b;
}

__global__ __launch_bounds__(512, 1) void fps_kernel(const float* __restrict__ xyz,
                                                     int* __restrict__ ctrIdx,
                                                     float* __restrict__ outCtr) {
  __shared__ float4 sxyz[N_PTS];                    // 128 KB
  __shared__ int    cidx[M_CTR];                    // 8 KB
  __shared__ __align__(16) unsigned long long candK[2][8];

  const int b = blockIdx.x;
  const int t = threadIdx.x;
  const int lane = t & 63;
  const int w = t >> 6;
  const float* xb = xyz + (size_t)b * N_PTS * 3;

  float px[16], py[16], pz[16], mind[16];
#pragma unroll
  for (int s = 0; s < 16; ++s) {
    int pt = t + s * 512;
    float x = xb[pt * 3 + 0];
    float y = xb[pt * 3 + 1];
    float z = xb[pt * 3 + 2];
    px[s] = x; py[s] = y; pz[s] = z;
    mind[s] = INFINITY;
    sxyz[pt] = make_float4(x, y, z, 0.f);
  }
  unsigned lo16[16];
#pragma unroll
  for (int s = 0; s < 16; ++s) lo16[s] = ~(unsigned)(t + s * 512);
  __syncthreads();

  int last = 0;
  for (int m = 0; m < M_CTR; ++m) {
    if (t == 0) cidx[m] = last;
    float4 lp = sxyz[last];                          // uniform broadcast
#pragma unroll
    for (int s = 0; s < 16; ++s) {
      float dx = __fsub_rn(px[s], lp.x);
      float dy = __fsub_rn(py[s], lp.y);
      float dz = __fsub_rn(pz[s], lp.z);
      float d2 = __fadd_rn(__fadd_rn(__fmul_rn(dx, dx), __fmul_rn(dy, dy)),
                           __fmul_rn(dz, dz));
      mind[s] = fminf(mind[s], d2);
    }
    unsigned long long key[16];
#pragma unroll
    for (int s = 0; s < 16; ++s)
      key[s] = ((unsigned long long)__float_as_uint(mind[s]) << 32) | lo16[s];
    // per-thread tree max (depth 4)
#pragma unroll
    for (int i = 0; i < 8; ++i) key[i] = maxu64(key[i], key[i + 8]);
#pragma unroll
    for (int i = 0; i < 4; ++i) key[i] = maxu64(key[i], key[i + 4]);
    key[0] = maxu64(key[0], key[2]);
    key[1] = maxu64(key[1], key[3]);
    unsigned long long k0 = maxu64(key[0], key[1]);
    // wave reduce: 4 DPP stages (VALU) + xor16 swizzle + xor32 shfl
    k0 = dpp_max_u64<0xB1>(k0);     // quad_perm xor1
    k0 = dpp_max_u64<0x4E>(k0);     // quad_perm xor2
    k0 = dpp_max_u64<0x141>(k0);    // row_half_mirror = xor7 -> half-row max
    k0 = dpp_max_u64<0x140>(k0);    // row_mirror = xor15 -> full row-of-16 max
    k0 = swz16_max_u64(k0);         // xor16
    k0 = maxu64(k0, (unsigned long long)__shfl_xor((unsigned long long)k0, 32, 64));
    const int buf = m & 1;
    if (lane == 0) candK[buf][w] = k0;
    __syncthreads();
    // cross-wave: 8 candidates, b128 loads + depth-3 tree (all threads)
    const ulonglong2* ck = (const ulonglong2*)&candK[buf][0];
    ulonglong2 c0v = ck[0], c1v = ck[1], c2v = ck[2], c3v = ck[3];
    unsigned long long m0 = maxu64(c0v.x, c0v.y);
    unsigned long long m1 = maxu64(c1v.x, c1v.y);
    unsigned long long m2 = maxu64(c2v.x, c2v.y);
    unsigned long long m3 = maxu64(c3v.x, c3v.y);
    unsigned long long best = maxu64(maxu64(m0, m1), maxu64(m2, m3));
    last = (int)(~(unsigned)best);
  }
  __syncthreads();
  for (int m = t; m < M_CTR; m += 512) {
    int ci = cidx[m];
    ctrIdx[b * M_CTR + m] = ci;
    float4 c = sxyz[ci];
    float* o = outCtr + (size_t)(b * M_CTR + m) * 3;
    o[0] = c.x; o[1] = c.y; o[2] = c.z;
  }
}

// ---------------------------------------------------------------------------
// Ball query: one wave per center; first K=32 ascending indices with d2<0.25
// (exact f32, no contraction). raw idx = -1 for pad slots.
// ---------------------------------------------------------------------------
__global__ __launch_bounds__(256) void ballq_kernel(const float* __restrict__ xyz,
                                                    const int* __restrict__ ctrIdx,
                                                    int* __restrict__ rawIdx) {
  const int cm   = blockIdx.x * 4 + (threadIdx.x >> 6);
  const int lane = threadIdx.x & 63;
  const int b    = cm >> 11;
  const float* xb = xyz + (size_t)b * N_PTS * 3;
  const int ci = ctrIdx[cm];
  const float cx = xb[ci * 3 + 0], cy = xb[ci * 3 + 1], cz = xb[ci * 3 + 2];
  int* out = rawIdx + (size_t)cm * KNB;
  int have = 0;
  for (int base = 0; base < N_PTS; base += 64) {
    int pt = base + lane;
    float dx = __fsub_rn(cx, xb[pt * 3 + 0]);
    float dy = __fsub_rn(cy, xb[pt * 3 + 1]);
    float dz = __fsub_rn(cz, xb[pt * 3 + 2]);
    float d2 = __fadd_rn(__fadd_rn(__fmul_rn(dx, dx), __fmul_rn(dy, dy)),
                         __fmul_rn(dz, dz));
    bool hit = d2 < 0.25f;
    unsigned long long mask = __ballot(hit);
    if (hit) {
      int rank = have + __popcll(mask & ((1ull << lane) - 1ull));
      if (rank < KNB) out[rank] = pt;
    }
    have += __popcll(mask);
    if (have >= KNB) break;
  }
  if (lane < KNB && lane >= have) out[lane] = -1;
}

// ---------------------------------------------------------------------------
// Fused per-center transformer v2.1. One block (256 thr) per center.
// Matmuls: thread = (cg: 8 cols, rowgroup: 4 rows, k-half kk); k-split
// reduced via __shfl_xor(.,32). LN stats via in-wave butterfly. Attention:
// thread=(head,row), fully in registers, zero barriers. Weight loads deep-
// pipelined (unroll 4 -> 4 kb-steps of L2 loads in flight).
// ---------------------------------------------------------------------------
struct SAParams {
  const float* xyz; const float* feats;
  const float* W_in; const float* b_in; const float* ln_in_g; const float* ln_in_b;
  const float* W_pos; const float* b_pos;
  const float* Wq; const float* bq; const float* Wk; const float* bk;
  const float* Wv; const float* bv; const float* Wo; const float* bo;
  const float* ln1_g; const float* ln1_b;
  const float* W1; const float* b1; const float* W2; const float* b2;
  const float* ln2_g; const float* ln2_b; const float* out_g; const float* out_b;
  const int* ctrIdx; const int* rawIdx;
  float* out;
};

// acc[4 rows][8 cols] += src[r0..r0+4][k0..k0+KH] * W[k][c0..c0+8]
template<int KH, int RS>
__device__ __forceinline__ void mm_rb(const float* __restrict__ src, int r0, int k0,
                                      const float* __restrict__ W, int ldw, int c0,
                                      float (&acc)[4][8]) {
#pragma unroll 4
  for (int kb = 0; kb < KH; kb += 4) {
    const int k = k0 + kb;
    float4 xv0 = *(const float4*)(src + (r0 + 0) * RS + k);
    float4 xv1 = *(const float4*)(src + (r0 + 1) * RS + k);
    float4 xv2 = *(const float4*)(src + (r0 + 2) * RS + k);
    float4 xv3 = *(const float4*)(src + (r0 + 3) * RS + k);
    const float* wr = W + (size_t)k * ldw + c0;
#pragma unroll
    for (int u = 0; u < 4; ++u) {
      float4 wa = *(const float4*)(wr + (size_t)u * ldw);
      float4 wb = *(const float4*)(wr + (size_t)u * ldw + 4);
      float xk0 = (&xv0.x)[u], xk1 = (&xv1.x)[u];
      float xk2 = (&xv2.x)[u], xk3 = (&xv3.x)[u];
#pragma unroll
      for (int j = 0; j < 4; ++j) {
        float wav = (&wa.x)[j], wbv = (&wb.x)[j];
        acc[0][j]     = fmaf(xk0, wav, acc[0][j]);
        acc[1][j]     = fmaf(xk1, wav, acc[1][j]);
        acc[2][j]     = fmaf(xk2, wav, acc[2][j]);
        acc[3][j]     = fmaf(xk3, wav, acc[3][j]);
        acc[0][4 + j] = fmaf(xk0, wbv, acc[0][4 + j]);
        acc[1][4 + j] = fmaf(xk1, wbv, acc[1][4 + j]);
        acc[2][4 + j] = fmaf(xk2, wbv, acc[2][4 + j]);
        acc[3][4 + j] = fmaf(xk3, wbv, acc[3][4 + j]);
      }
    }
  }
}

__device__ __forceinline__ void xchg_add(float (&acc)[4][8]) {
#pragma unroll
  for (int i = 0; i < 4; ++i)
#pragma unroll
    for (int j = 0; j < 8; ++j)
      acc[i][j] += __shfl_xor(acc[i][j], 32, 64);
}

__device__ __forceinline__ void add_bias(float (&acc)[4][8], const float* bptr, int c0) {
  float4 ba = *(const float4*)(bptr + c0);
  float4 bb = *(const float4*)(bptr + c0 + 4);
#pragma unroll
  for (int i = 0; i < 4; ++i)
#pragma unroll
    for (int j = 0; j < 4; ++j) {
      acc[i][j]     += (&ba.x)[j];
      acc[i][4 + j] += (&bb.x)[j];
    }
}

// mean/inv-std per row (butterfly over cg lanes: bits 0..3)
__device__ __forceinline__ void row_stats(const float (&acc)[4][8],
                                          float (&mean)[4], float (&inv)[4]) {
#pragma unroll
  for (int i = 0; i < 4; ++i) {
    float s = 0.f, sq = 0.f;
#pragma unroll
    for (int j = 0; j < 8; ++j) { s += acc[i][j]; sq += acc[i][j] * acc[i][j]; }
#pragma unroll
    for (int off = 1; off < 16; off <<= 1) {
      s  += __shfl_xor(s,  off, 64);
      sq += __shfl_xor(sq, off, 64);
    }
    float mn = s * (1.0f / CH);
    float var = fmaxf(sq * (1.0f / CH) - mn * mn, 0.f);
    mean[i] = mn;
    inv[i]  = rsqrtf(var + 1e-5f);
  }
}

__global__ __launch_bounds__(256, 2) void sa_kernel(SAParams p) {
  __shared__ float smem[4 * KNB * TP];      // xs | qs | ksb | vsb
  __shared__ int   nidx[KNB];
  __shared__ int   padf[KNB];
  __shared__ float nxs[KNB], nys[KNB], nzs[KNB];
  __shared__ float psum[2][2];

  float* const xsb  = smem;
  float* const qsb  = smem + KNB * TP;
  float* const ksbb = smem + 2 * KNB * TP;
  float* const vsbb = smem + 3 * KNB * TP;

  const int t    = threadIdx.x;
  const int lane = t & 63;
  const int w    = t >> 6;
  const int cg   = lane & 15;
  const int rgL  = (lane >> 4) & 1;
  const int kk   = (lane >> 5) & 1;
  const int r0   = w * 8 + rgL * 4;
  const int c0   = cg * 8;
  const int cm   = blockIdx.x;
  const int b    = cm >> 11;

  if (t < KNB) {
    int raw = p.rawIdx[(size_t)cm * KNB + t];
    int ci  = p.ctrIdx[cm];
    int ni  = (raw < 0) ? ci : raw;
    nidx[t] = ni;
    padf[t] = (raw < 0) ? 1 : 0;
    const float* q = p.xyz + ((size_t)b * N_PTS + ni) * 3;
    nxs[t] = q[0]; nys[t] = q[1]; nzs[t] = q[2];
  }
  __syncthreads();

  // ---- gather feats into fs (= qs region) as [32][68] ----
  float* const fsb = qsb;                 // stride 68
  for (int e = t; e < KNB * CIN; e += 256) {
    int rr = e >> 6, cc = e & 63;
    fsb[rr * 68 + cc] = p.feats[((size_t)b * N_PTS + nidx[rr]) * CIN + cc];
  }
  __syncthreads();

  // ---- in-proj + LN + relu + posenc -> xs ----
  {
    float acc[4][8] = {};
    mm_rb<32, 68>(fsb, r0, kk * 32, p.W_in, CH, c0, acc);
    xchg_add(acc);
    add_bias(acc, p.b_in, c0);
    float mean[4], inv[4];
    row_stats(acc, mean, inv);
    float4 g  = *(const float4*)(p.ln_in_g + c0 + kk * 4);
    float4 bt = *(const float4*)(p.ln_in_b + c0 + kk * 4);
    float4 w0 = *(const float4*)(p.W_pos + 0 * CH + c0 + kk * 4);
    float4 w1 = *(const float4*)(p.W_pos + 1 * CH + c0 + kk * 4);
    float4 w2 = *(const float4*)(p.W_pos + 2 * CH + c0 + kk * 4);
    float4 bp = *(const float4*)(p.b_pos + c0 + kk * 4);
#pragma unroll
    for (int i = 0; i < 4; ++i) {
      int r = r0 + i;
      float x = nxs[r], y = nys[r], z = nzs[r];
      float4 o;
#pragma unroll
      for (int j = 0; j < 4; ++j) {
        float hv = (acc[i][kk * 4 + j] - mean[i]) * inv[i] * (&g.x)[j] + (&bt.x)[j];
        hv = fmaxf(hv, 0.f);
        float pos = fmaf(x, (&w0.x)[j], fmaf(y, (&w1.x)[j],
                     fmaf(z, (&w2.x)[j], (&bp.x)[j])));
        (&o.x)[j] = hv + pos;
      }
      *(float4*)(xsb + r * TP + c0 + kk * 4) = o;
    }
  }
  __syncthreads();

  // ---- q, k, v (q pre-scaled by 1/sqrt(Dh)=0.25 — exact pow2) ----
  {
    float acc[4][8] = {};
    mm_rb<64, TP>(xsb, r0, kk * 64, p.Wq, CH, c0, acc);
    xchg_add(acc);
    add_bias(acc, p.bq, c0);
#pragma unroll
    for (int i = 0; i < 4; ++i) {
      float4 o;
#pragma unroll
      for (int j = 0; j < 4; ++j) (&o.x)[j] = acc[i][kk * 4 + j] * 0.25f;
      *(float4*)(qsb + (r0 + i) * TP + c0 + kk * 4) = o;
    }
  }
  {
    float acc[4][8] = {};
    mm_rb<64, TP>(xsb, r0, kk * 64, p.Wk, CH, c0, acc);
    xchg_add(acc);
    add_bias(acc, p.bk, c0);
#pragma unroll
    for (int i = 0; i < 4; ++i) {
      float4 o;
#pragma unroll
      for (int j = 0; j < 4; ++j) (&o.x)[j] = acc[i][kk * 4 + j];
      *(float4*)(ksbb + (r0 + i) * TP + c0 + kk * 4) = o;
    }
  }
  {
    float acc[4][8] = {};
    mm_rb<64, TP>(xsb, r0, kk * 64, p.Wv, CH, c0, acc);
    xchg_add(acc);
    add_bias(acc, p.bv, c0);
#pragma unroll
    for (int i = 0; i < 4; ++i) {
      float4 o;
#pragma unroll
      for (int j = 0; j < 4; ++j) (&o.x)[j] = acc[i][kk * 4 + j];
      *(float4*)(vsbb + (r0 + i) * TP + c0 + kk * 4) = o;
    }
  }
  __syncthreads();

  // ---- attention: thread = (head h, row i); all in registers ----
  {
    const int h  = t >> 5;
    const int qi = t & 31;
    float qv[16];
#pragma unroll
    for (int c = 0; c < 4; ++c)
      *(float4*)&qv[c * 4] = *(const float4*)(qsb + qi * TP + h * DH + c * 4);
    float sc[KNB];
#pragma unroll
    for (int j = 0; j < KNB; ++j) {
      float d = 0.f;
#pragma unroll
      for (int c = 0; c < 4; ++c) {
        float4 kv = *(const float4*)(ksbb + j * TP + h * DH + c * 4);
#pragma unroll
        for (int e = 0; e < 4; ++e) d = fmaf(qv[c * 4 + e], (&kv.x)[e], d);
      }
      sc[j] = padf[j] ? -1e9f : d;
    }
    float mx = -INFINITY;
#pragma unroll
    for (int j = 0; j < KNB; ++j) mx = fmaxf(mx, sc[j]);
    float se = 0.f;
#pragma unroll
    for (int j = 0; j < KNB; ++j) { sc[j] = expf(sc[j] - mx); se += sc[j]; }
    float isum = 1.0f / se;
    float ov[16] = {};
#pragma unroll
    for (int j = 0; j < KNB; ++j) {
      float pj = sc[j];
#pragma unroll
      for (int c = 0; c < 4; ++c) {
        float4 vv = *(const float4*)(vsbb + j * TP + h * DH + c * 4);
#pragma unroll
        for (int e = 0; e < 4; ++e)
          ov[c * 4 + e] = fmaf(pj, (&vv.x)[e], ov[c * 4 + e]);
      }
    }
#pragma unroll
    for (int c = 0; c < 4; ++c) {
      float4 o;
#pragma unroll
      for (int e = 0; e < 4; ++e) (&o.x)[e] = ov[c * 4 + e] * isum;
      *(float4*)(qsb + qi * TP + h * DH + c * 4) = o;   // own slice; q already read
    }
  }
  __syncthreads();

  // ---- x = LN1(x + o @ Wo + bo) ----
  {
    float acc[4][8] = {};
    mm_rb<64, TP>(qsb, r0, kk * 64, p.Wo, CH, c0, acc);
    xchg_add(acc);
    add_bias(acc, p.bo, c0);
#pragma unroll
    for (int i = 0; i < 4; ++i) {
      float4 ra = *(const float4*)(xsb + (r0 + i) * TP + c0);
      float4 rb = *(const float4*)(xsb + (r0 + i) * TP + c0 + 4);
#pragma unroll
      for (int j = 0; j < 4; ++j) { acc[i][j] += (&ra.x)[j]; acc[i][4 + j] += (&rb.x)[j]; }
    }
    float mean[4], inv[4];
    row_stats(acc, mean, inv);
    float4 g  = *(const float4*)(p.ln1_g + c0 + kk * 4);
    float4 bt = *(const float4*)(p.ln1_b + c0 + kk * 4);
#pragma unroll
    for (int i = 0; i < 4; ++i) {
      float4 o;
#pragma unroll
      for (int j = 0; j < 4; ++j)
        (&o.x)[j] = (acc[i][kk * 4 + j] - mean[i]) * inv[i] * (&g.x)[j] + (&bt.x)[j];
      *(float4*)(xsb + (r0 + i) * TP + c0 + kk * 4) = o;
    }
  }
  __syncthreads();

  // ---- FFN: x = LN2(x + relu(x@W1+b1)@W2 + b2), hidden in 4 chunks of 128 ----
  {
    float acc2[4][8] = {};
    for (int cb = 0; cb < 4; ++cb) {
      float acch[4][8] = {};
      mm_rb<64, TP>(xsb, r0, kk * 64, p.W1 + cb * CH, 4 * CH, c0, acch);
      xchg_add(acch);
      add_bias(acch, p.b1 + cb * CH, c0);
#pragma unroll
      for (int i = 0; i < 4; ++i) {
        float4 o;
#pragma unroll
        for (int j = 0; j < 4; ++j) (&o.x)[j] = fmaxf(acch[i][kk * 4 + j], 0.f);
        *(float4*)(ksbb + (r0 + i) * TP + c0 + kk * 4) = o;
      }
      __syncthreads();
      mm_rb<64, TP>(ksbb, r0, kk * 64, p.W2 + (size_t)cb * CH * CH, CH, c0, acc2);
      __syncthreads();
    }
    xchg_add(acc2);
    add_bias(acc2, p.b2, c0);
#pragma unroll
    for (int i = 0; i < 4; ++i) {
      float4 ra = *(const float4*)(xsb + (r0 + i) * TP + c0);
      float4 rb = *(const float4*)(xsb + (r0 + i) * TP + c0 + 4);
#pragma unroll
      for (int j = 0; j < 4; ++j) { acc2[i][j] += (&ra.x)[j]; acc2[i][4 + j] += (&rb.x)[j]; }
    }
    float mean[4], inv[4];
    row_stats(acc2, mean, inv);
    float4 g  = *(const float4*)(p.ln2_g + c0 + kk * 4);
    float4 bt = *(const float4*)(p.ln2_b + c0 + kk * 4);
#pragma unroll
    for (int i = 0; i < 4; ++i) {
      float4 o;
#pragma unroll
      for (int j = 0; j < 4; ++j)
        (&o.x)[j] = (acc2[i][kk * 4 + j] - mean[i]) * inv[i] * (&g.x)[j] + (&bt.x)[j];
      *(float4*)(xsb + (r0 + i) * TP + c0 + kk * 4) = o;
    }
  }
  __syncthreads();

  // ---- max-pool over K + LN(out) ----
  float pmax = -INFINITY;
  if (t < CH) {
#pragma unroll 8
    for (int rr = 0; rr < KNB; ++rr) pmax = fmaxf(pmax, xsb[rr * TP + t]);
    float s = pmax, sq = pmax * pmax;
#pragma unroll
    for (int off = 1; off < 64; off <<= 1) {
      s  += __shfl_xor(s,  off, 64);
      sq += __shfl_xor(sq, off, 64);
    }
    if (lane == 0) { psum[w][0] = s; psum[w][1] = sq; }
  }
  __syncthreads();
  if (t < CH) {
    float s = psum[0][0] + psum[1][0];
    float sq = psum[0][1] + psum[1][1];
    float mean = s * (1.0f / CH);
    float var = fmaxf(sq * (1.0f / CH) - mean * mean, 0.f);
    float inv = rsqrtf(var + 1e-5f);
    float v = (pmax - mean) * inv * p.out_g[t] + p.out_b[t];
    p.out[(size_t)BATCH * M_CTR * 3 + (size_t)cm * CH + t] = v;
  }
}

// ---------------------------------------------------------------------------
extern "C" void kernel_launch(void* const* d_in, const int* in_sizes, int n_in,
                              void* d_out, int out_size, void* d_ws, size_t ws_size,
                              hipStream_t stream) {
  const float* xyz     = (const float*)d_in[0];
  const float* feats   = (const float*)d_in[1];
  const float* W_in    = (const float*)d_in[2];
  const float* b_in    = (const float*)d_in[3];
  const float* ln_in_g = (const float*)d_in[4];
  const float* ln_in_b = (const float*)d_in[5];
  const float* W_pos   = (const float*)d_in[6];
  const float* b_pos   = (const float*)d_in[7];
  const float* Wq      = (const float*)d_in[8];
  const float* bq      = (const float*)d_in[9];
  const float* Wk      = (const float*)d_in[10];
  const float* bk      = (const float*)d_in[11];
  const float* Wv      = (const float*)d_in[12];
  const float* bv      = (const float*)d_in[13];
  const float* Wo      = (const float*)d_in[14];
  const float* bo      = (const float*)d_in[15];
  const float* ln1_g   = (const float*)d_in[16];
  const float* ln1_b   = (const float*)d_in[17];
  const float* W1      = (const float*)d_in[18];
  const float* b1      = (const float*)d_in[19];
  const float* W2      = (const float*)d_in[20];
  const float* b2      = (const float*)d_in[21];
  const float* ln2_g   = (const float*)d_in[22];
  const float* ln2_b   = (const float*)d_in[23];
  const float* out_g   = (const float*)d_in[24];
  const float* out_b   = (const float*)d_in[25];
  float* out = (float*)d_out;

  int* wsCtr = (int*)d_ws;                 // B*M ints
  int* wsRaw = wsCtr + BATCH * M_CTR;      // B*M*K ints

  fps_kernel<<<BATCH, 512, 0, stream>>>(xyz, wsCtr, out);
  ballq_kernel<<<(BATCH * M_CTR) / 4, 256, 0, stream>>>(xyz, wsCtr, wsRaw);

  SAParams p{xyz, feats, W_in, b_in, ln_in_g, ln_in_b, W_pos, b_pos,
             Wq, bq, Wk, bk, Wv, bv, Wo, bo, ln1_g, ln1_b,
             W1, b1, W2, b2, ln2_g, ln2_b, out_g, out_b,
             wsCtr, wsRaw, out};
  sa_kernel<<<BATCH * M_CTR, 256, 0, stream>>>(p);
}

// Round 6
// 2348.430 us; speedup vs baseline: 2.8461x; 1.4131x over previous
//
#include <hip/hip_runtime.h>
#include <math.h>

#define N_PTS 8192
#define BATCH 2
#define M_CTR 2048
#define KNB   32
#define CIN   64
#define CH    128
#define NHEAD 8
#define DH    16

typedef __attribute__((ext_vector_type(4))) float f32x4;
typedef __attribute__((ext_vector_type(8))) short bf16x8;

// ---------------------------------------------------------------------------
// FPS v5 (unchanged from passing round): exact f32 distances, u64-key argmax,
// DPP xor1/xor2/xor7/xor15 + swizzle xor16 + shfl xor32 all-reduce.
// ---------------------------------------------------------------------------
template<int CTRL>
__device__ __forceinline__ unsigned long long dpp_max_u64(unsigned long long k) {
  int lo = (int)(unsigned)k;
  int hi = (int)(k >> 32);
  int lo2 = __builtin_amdgcn_update_dpp(0, lo, CTRL, 0xF, 0xF, true);
  int hi2 = __builtin_amdgcn_update_dpp(0, hi, CTRL, 0xF, 0xF, true);
  unsigned long long o = ((unsigned long long)(unsigned)hi2 << 32) | (unsigned)lo2;
  return o > k ? o : k;
}

__device__ __forceinline__ unsigned long long swz16_max_u64(unsigned long long k) {
  int lo = (int)(unsigned)k;
  int hi = (int)(k >> 32);
  int lo2 = __builtin_amdgcn_ds_swizzle(lo, 0x401F);   // xor 16
  int hi2 = __builtin_amdgcn_ds_swizzle(hi, 0x401F);
  unsigned long long o = ((unsigned long long)(unsigned)hi2 << 32) | (unsigned)lo2;
  return o > k ? o : k;
}

__device__ __forceinline__ unsigned long long maxu64(unsigned long long a,
                                                     unsigned long long b) {
  return a > b ? a : b;
}

__global__ __launch_bounds__(512, 1) void fps_kernel(const float* __restrict__ xyz,
                                                     int* __restrict__ ctrIdx,
                                                     float* __restrict__ outCtr) {
  __shared__ float4 sxyz[N_PTS];
  __shared__ int    cidx[M_CTR];
  __shared__ __align__(16) unsigned long long candK[2][8];

  const int b = blockIdx.x;
  const int t = threadIdx.x;
  const int lane = t & 63;
  const int w = t >> 6;
  const float* xb = xyz + (size_t)b * N_PTS * 3;

  float px[16], py[16], pz[16], mind[16];
#pragma unroll
  for (int s = 0; s < 16; ++s) {
    int pt = t + s * 512;
    float x = xb[pt * 3 + 0];
    float y = xb[pt * 3 + 1];
    float z = xb[pt * 3 + 2];
    px[s] = x; py[s] = y; pz[s] = z;
    mind[s] = INFINITY;
    sxyz[pt] = make_float4(x, y, z, 0.f);
  }
  unsigned lo16[16];
#pragma unroll
  for (int s = 0; s < 16; ++s) lo16[s] = ~(unsigned)(t + s * 512);
  __syncthreads();

  int last = 0;
  for (int m = 0; m < M_CTR; ++m) {
    if (t == 0) cidx[m] = last;
    float4 lp = sxyz[last];
#pragma unroll
    for (int s = 0; s < 16; ++s) {
      float dx = __fsub_rn(px[s], lp.x);
      float dy = __fsub_rn(py[s], lp.y);
      float dz = __fsub_rn(pz[s], lp.z);
      float d2 = __fadd_rn(__fadd_rn(__fmul_rn(dx, dx), __fmul_rn(dy, dy)),
                           __fmul_rn(dz, dz));
      mind[s] = fminf(mind[s], d2);
    }
    unsigned long long key[16];
#pragma unroll
    for (int s = 0; s < 16; ++s)
      key[s] = ((unsigned long long)__float_as_uint(mind[s]) << 32) | lo16[s];
#pragma unroll
    for (int i = 0; i < 8; ++i) key[i] = maxu64(key[i], key[i + 8]);
#pragma unroll
    for (int i = 0; i < 4; ++i) key[i] = maxu64(key[i], key[i + 4]);
    key[0] = maxu64(key[0], key[2]);
    key[1] = maxu64(key[1], key[3]);
    unsigned long long k0 = maxu64(key[0], key[1]);
    k0 = dpp_max_u64<0xB1>(k0);     // quad_perm xor1
    k0 = dpp_max_u64<0x4E>(k0);     // quad_perm xor2
    k0 = dpp_max_u64<0x141>(k0);    // row_half_mirror (xor7)
    k0 = dpp_max_u64<0x140>(k0);    // row_mirror (xor15)
    k0 = swz16_max_u64(k0);
    k0 = maxu64(k0, (unsigned long long)__shfl_xor((unsigned long long)k0, 32, 64));
    const int buf = m & 1;
    if (lane == 0) candK[buf][w] = k0;
    __syncthreads();
    const ulonglong2* ck = (const ulonglong2*)&candK[buf][0];
    ulonglong2 c0v = ck[0], c1v = ck[1], c2v = ck[2], c3v = ck[3];
    unsigned long long m0 = maxu64(c0v.x, c0v.y);
    unsigned long long m1 = maxu64(c1v.x, c1v.y);
    unsigned long long m2 = maxu64(c2v.x, c2v.y);
    unsigned long long m3 = maxu64(c3v.x, c3v.y);
    unsigned long long best = maxu64(maxu64(m0, m1), maxu64(m2, m3));
    last = (int)(~(unsigned)best);
  }
  __syncthreads();
  for (int m = t; m < M_CTR; m += 512) {
    int ci = cidx[m];
    ctrIdx[b * M_CTR + m] = ci;
    float4 c = sxyz[ci];
    float* o = outCtr + (size_t)(b * M_CTR + m) * 3;
    o[0] = c.x; o[1] = c.y; o[2] = c.z;
  }
}

// ---------------------------------------------------------------------------
// Ball query (unchanged).
// ---------------------------------------------------------------------------
__global__ __launch_bounds__(256) void ballq_kernel(const float* __restrict__ xyz,
                                                    const int* __restrict__ ctrIdx,
                                                    int* __restrict__ rawIdx) {
  const int cm   = blockIdx.x * 4 + (threadIdx.x >> 6);
  const int lane = threadIdx.x & 63;
  const int b    = cm >> 11;
  const float* xb = xyz + (size_t)b * N_PTS * 3;
  const int ci = ctrIdx[cm];
  const float cx = xb[ci * 3 + 0], cy = xb[ci * 3 + 1], cz = xb[ci * 3 + 2];
  int* out = rawIdx + (size_t)cm * KNB;
  int have = 0;
  for (int base = 0; base < N_PTS; base += 64) {
    int pt = base + lane;
    float dx = __fsub_rn(cx, xb[pt * 3 + 0]);
    float dy = __fsub_rn(cy, xb[pt * 3 + 1]);
    float dz = __fsub_rn(cz, xb[pt * 3 + 2]);
    float d2 = __fadd_rn(__fadd_rn(__fmul_rn(dx, dx), __fmul_rn(dy, dy)),
                         __fmul_rn(dz, dz));
    bool hit = d2 < 0.25f;
    unsigned long long mask = __ballot(hit);
    if (hit) {
      int rank = have + __popcll(mask & ((1ull << lane) - 1ull));
      if (rank < KNB) out[rank] = pt;
    }
    have += __popcll(mask);
    if (have >= KNB) break;
  }
  if (lane < KNB && lane >= have) out[lane] = -1;
}

// ---------------------------------------------------------------------------
// Weight prep: transpose all weights to bf16 Wt[c][k] in workspace so MFMA
// B-fragments (k-contiguous at fixed output col) read directly from L2.
// Offsets (shorts): Wint 0 (8192), Wq 8192, Wk 24576, Wv 40960, Wo 57344,
// W1t 73728 (65536, [512][128]), W2t 139264 (65536, [128][512]). total 204800.
// ---------------------------------------------------------------------------
__device__ __forceinline__ unsigned short f2bf(float f) {
  unsigned u = __float_as_uint(f);
  unsigned r = (u + 0x7FFFu + ((u >> 16) & 1u)) >> 16;   // RNE
  return (unsigned short)r;
}
__device__ __forceinline__ float bf2f(unsigned short s) {
  return __uint_as_float(((unsigned)s) << 16);
}

__global__ __launch_bounds__(256) void prep_kernel(const float* __restrict__ W_in,
    const float* __restrict__ Wq, const float* __restrict__ Wk,
    const float* __restrict__ Wv, const float* __restrict__ Wo,
    const float* __restrict__ W1, const float* __restrict__ W2,
    short* __restrict__ wsW) {
  int i = blockIdx.x * 256 + threadIdx.x;
  if (i >= 204800) return;
  const float* src; int K, C, off;
  if (i < 8192)        { src = W_in; K = 64;  C = 128; off = i; }
  else if (i < 24576)  { src = Wq;   K = 128; C = 128; off = i - 8192; }
  else if (i < 40960)  { src = Wk;   K = 128; C = 128; off = i - 24576; }
  else if (i < 57344)  { src = Wv;   K = 128; C = 128; off = i - 40960; }
  else if (i < 73728)  { src = Wo;   K = 128; C = 128; off = i - 57344; }
  else if (i < 139264) { src = W1;   K = 128; C = 512; off = i - 73728; }
  else                 { src = W2;   K = 512; C = 128; off = i - 139264; }
  int c = off / K, k = off - c * K;
  wsW[i] = (short)f2bf(src[(size_t)k * C + c]);
}

// ---------------------------------------------------------------------------
// Fused per-center transformer v3: MFMA bf16. 128 thr = 2 waves per center.
// Wave w = row-tile (neighbors w*16..w*16+15). All matmuls via
// mfma_f32_16x16x32_bf16: A = activations (LDS bf16, rows k-contig),
// B = transposed weights (global bf16, k-contig). C-frag: row=(l>>4)*4+r,
// col=l&15 [m89]. A-frag: row=l&15, k=(l>>4)*8+j. B-frag: col=l&15,
// k=(l>>4)*8+j. LN stats fully in-wave via exact DPP butterfly
// (xor1,xor2,xor7,xor15 = all-reduce over 16 lanes, HW-verified in fps).
// ---------------------------------------------------------------------------
#define XS  136   // activation LDS row stride (shorts): 272B, 16B-aligned
#define VTS 40    // vT row stride: 80B aligned
#define PS  264   // P row stride: 528B aligned

struct SAParams {
  const float* xyz; const float* feats;
  const float* b_in; const float* ln_in_g; const float* ln_in_b;
  const float* W_pos; const float* b_pos;
  const float* bq; const float* bk; const float* bv; const float* bo;
  const float* ln1_g; const float* ln1_b;
  const float* b1; const float* b2;
  const float* ln2_g; const float* ln2_b; const float* out_g; const float* out_b;
  const short* wsW;
  const int* ctrIdx; const int* rawIdx;
  float* out;
};

template<int C>
__device__ __forceinline__ float dppf(float v) {
  return __int_as_float(__builtin_amdgcn_update_dpp(0, __float_as_int(v), C, 0xF, 0xF, true));
}
__device__ __forceinline__ float red16_add(float v) {
  v += dppf<0xB1>(v);  v += dppf<0x4E>(v);
  v += dppf<0x141>(v); v += dppf<0x140>(v);
  return v;
}
__device__ __forceinline__ float red16_max(float v) {
  v = fmaxf(v, dppf<0xB1>(v));  v = fmaxf(v, dppf<0x4E>(v));
  v = fmaxf(v, dppf<0x141>(v)); v = fmaxf(v, dppf<0x140>(v));
  return v;
}

// acc[ct] += A(16x(32*NKS)) * B; A from LDS (own row-tile), B from global Wt.
template<int NCT, int NKS>
__device__ __forceinline__ void mm_mfma(const short* __restrict__ albase, int lstr,
                                        const short* __restrict__ wt, int wK,
                                        f32x4 (&acc)[NCT], int l15, int lg) {
#pragma unroll
  for (int ks = 0; ks < NKS; ++ks) {
    bf16x8 a = *(const bf16x8*)(albase + l15 * lstr + ks * 32 + lg * 8);
#pragma unroll
    for (int ct = 0; ct < NCT; ++ct) {
      bf16x8 bf = *(const bf16x8*)(wt + (size_t)(ct * 16 + l15) * wK + ks * 32 + lg * 8);
      acc[ct] = __builtin_amdgcn_mfma_f32_16x16x32_bf16(a, bf, acc[ct], 0, 0, 0);
    }
  }
}

__global__ __launch_bounds__(128, 1) void sa_kernel(SAParams p) {
  __shared__ short sm[3 * 32 * XS + 128 * VTS + 32 * PS];
  __shared__ float nxs[32], nys[32], nzs[32];
  __shared__ int   nidx[32];
  __shared__ unsigned padmaskS;
  __shared__ float psum[2][2];

  short* const xb  = sm;                          // x activations [32][XS]
  short* const qb  = sm + 32 * XS;                // q, later o
  short* const kb  = sm + 2 * 32 * XS;            // k, later ffn hidden
  short* const vT  = sm + 3 * 32 * XS;            // V^T [128][VTS]
  short* const Pb  = sm + 3 * 32 * XS + 128 * VTS;// P [32][PS]; also feats staging
  short* const fsb = Pb;
  short* const ob  = qb;
  short* const hb  = kb;

  const int t    = threadIdx.x;
  const int lane = t & 63;
  const int rt   = t >> 6;            // wave = row tile
  const int l15  = lane & 15;
  const int lg   = lane >> 4;
  const int cm   = blockIdx.x;
  const int b    = cm >> 11;
  const short* arow = 0;

  // ---- stage 0: neighbor indices, coords, pad mask ----
  if (t < 32) {
    int raw = p.rawIdx[(size_t)cm * KNB + t];
    int ci  = p.ctrIdx[cm];
    int ni  = (raw < 0) ? ci : raw;
    nidx[t] = ni;
    const float* q = p.xyz + ((size_t)b * N_PTS + ni) * 3;
    nxs[t] = q[0]; nys[t] = q[1]; nzs[t] = q[2];
  }
  if (t < 64) {
    bool isPad = (t < 32) ? (p.rawIdx[(size_t)cm * KNB + t] < 0) : false;
    unsigned long long m = __ballot(isPad);
    if (t == 0) padmaskS = (unsigned)m;
  }
  __syncthreads();

  // ---- stage 1: gather feats -> fsb bf16 [32][72] ----
  {
    int row = t >> 2;
    int cs  = (t & 3) * 16;
    const float* src = p.feats + ((size_t)b * N_PTS + nidx[row]) * CIN + cs;
    float4 f0 = *(const float4*)(src + 0);
    float4 f1 = *(const float4*)(src + 4);
    float4 f2 = *(const float4*)(src + 8);
    float4 f3 = *(const float4*)(src + 12);
    unsigned short u[16];
#pragma unroll
    for (int j = 0; j < 4; ++j) {
      u[j]      = f2bf((&f0.x)[j]); u[4 + j]  = f2bf((&f1.x)[j]);
      u[8 + j]  = f2bf((&f2.x)[j]); u[12 + j] = f2bf((&f3.x)[j]);
    }
    uint4 w0, w1;
    unsigned* uw = (unsigned*)&w0;
#pragma unroll
    for (int j = 0; j < 8; ++j) ((unsigned*)&w0)[j < 4 ? j : j] = 0; // init quiet
    (void)uw;
    unsigned packed[8];
#pragma unroll
    for (int j = 0; j < 8; ++j) packed[j] = (unsigned)u[2 * j] | ((unsigned)u[2 * j + 1] << 16);
    w0 = make_uint4(packed[0], packed[1], packed[2], packed[3]);
    w1 = make_uint4(packed[4], packed[5], packed[6], packed[7]);
    *(uint4*)(fsb + row * 72 + cs)     = w0;
    *(uint4*)(fsb + row * 72 + cs + 8) = w1;
  }
  __syncthreads();

  const unsigned padmask = padmaskS;
  float rowxyz[3][4];
#pragma unroll
  for (int r = 0; r < 4; ++r) {
    int row = rt * 16 + lg * 4 + r;
    rowxyz[0][r] = nxs[row]; rowxyz[1][r] = nys[row]; rowxyz[2][r] = nzs[row];
  }

  // ---- stage 2: in-proj + LN + relu + posenc -> xb ----
  {
    f32x4 acc[8] = {};
    mm_mfma<8, 2>(fsb + rt * 16 * 72, 72, p.wsW + 0, 64, acc, l15, lg);
    float s[4] = {}, sq[4] = {};
#pragma unroll
    for (int ct = 0; ct < 8; ++ct) {
      float bia = p.b_in[ct * 16 + l15];
#pragma unroll
      for (int r = 0; r < 4; ++r) {
        acc[ct][r] += bia;
        s[r] += acc[ct][r]; sq[r] += acc[ct][r] * acc[ct][r];
      }
    }
    float mean[4], inv[4];
#pragma unroll
    for (int r = 0; r < 4; ++r) {
      float S = red16_add(s[r]), SQ = red16_add(sq[r]);
      mean[r] = S * (1.0f / CH);
      float var = fmaxf(SQ * (1.0f / CH) - mean[r] * mean[r], 0.f);
      inv[r] = rsqrtf(var + 1e-5f);
    }
#pragma unroll
    for (int ct = 0; ct < 8; ++ct) {
      int c = ct * 16 + l15;
      float g  = p.ln_in_g[c], bt = p.ln_in_b[c];
      float w0 = p.W_pos[0 * CH + c], w1 = p.W_pos[1 * CH + c];
      float w2 = p.W_pos[2 * CH + c], bp = p.b_pos[c];
#pragma unroll
      for (int r = 0; r < 4; ++r) {
        int row = rt * 16 + lg * 4 + r;
        float h = (acc[ct][r] - mean[r]) * inv[r] * g + bt;
        h = fmaxf(h, 0.f);
        float pos = fmaf(rowxyz[0][r], w0, fmaf(rowxyz[1][r], w1,
                    fmaf(rowxyz[2][r], w2, bp)));
        xb[row * XS + c] = (short)f2bf(h + pos);
      }
    }
  }
  __syncthreads();

  // ---- stage 3: q, k, v ----
  arow = xb + rt * 16 * XS;
  {
    f32x4 acc[8] = {};
    mm_mfma<8, 4>(arow, XS, p.wsW + 8192, 128, acc, l15, lg);
#pragma unroll
    for (int ct = 0; ct < 8; ++ct) {
      int c = ct * 16 + l15;
      float bia = p.bq[c];
#pragma unroll
      for (int r = 0; r < 4; ++r)
        qb[(rt * 16 + lg * 4 + r) * XS + c] = (short)f2bf((acc[ct][r] + bia) * 0.25f);
    }
  }
  {
    f32x4 acc[8] = {};
    mm_mfma<8, 4>(arow, XS, p.wsW + 24576, 128, acc, l15, lg);
#pragma unroll
    for (int ct = 0; ct < 8; ++ct) {
      int c = ct * 16 + l15;
      float bia = p.bk[c];
#pragma unroll
      for (int r = 0; r < 4; ++r)
        kb[(rt * 16 + lg * 4 + r) * XS + c] = (short)f2bf(acc[ct][r] + bia);
    }
  }
  {
    f32x4 acc[8] = {};
    mm_mfma<8, 4>(arow, XS, p.wsW + 40960, 128, acc, l15, lg);
#pragma unroll
    for (int ct = 0; ct < 8; ++ct) {
      int c = ct * 16 + l15;
      float bia = p.bv[c];
#pragma unroll
      for (int r = 0; r < 4; ++r)
        vT[c * VTS + rt * 16 + lg * 4 + r] = (short)f2bf(acc[ct][r] + bia);
    }
  }
  __syncthreads();

  // ---- stage 4: scores + softmax -> Pb (wave handles its 16 q rows) ----
  {
    bool pad0 = (padmask >> l15) & 1u;
    bool pad1 = (padmask >> (16 + l15)) & 1u;
    const bf16x8 z = {0, 0, 0, 0, 0, 0, 0, 0};
#pragma unroll
    for (int h = 0; h < NHEAD; ++h) {
      bf16x8 a = *(const bf16x8*)(qb + (rt * 16 + l15) * XS + h * DH + (lg & 1) * 8);
      if (lg >= 2) a = z;                       // zero-pad K 16..31
      bf16x8 b0 = *(const bf16x8*)(kb + (l15) * XS + h * DH + (lg & 1) * 8);
      bf16x8 b1 = *(const bf16x8*)(kb + (16 + l15) * XS + h * DH + (lg & 1) * 8);
      f32x4 s0 = {}, s1 = {};
      s0 = __builtin_amdgcn_mfma_f32_16x16x32_bf16(a, b0, s0, 0, 0, 0);
      s1 = __builtin_amdgcn_mfma_f32_16x16x32_bf16(a, b1, s1, 0, 0, 0);
#pragma unroll
      for (int r = 0; r < 4; ++r) {
        float v0 = pad0 ? -1e9f : s0[r];
        float v1 = pad1 ? -1e9f : s1[r];
        float mx = red16_max(fmaxf(v0, v1));
        float e0 = __expf(v0 - mx), e1 = __expf(v1 - mx);
        float sum = red16_add(e0 + e1);
        float isum = 1.0f / sum;
        int row = rt * 16 + lg * 4 + r;
        Pb[row * PS + h * 32 + l15]      = (short)f2bf(e0 * isum);
        Pb[row * PS + h * 32 + 16 + l15] = (short)f2bf(e1 * isum);
      }
    }
  }
  __syncthreads();   // Pb/vT ready; also protects kb before ffn reuse

  // ---- stage 5: PV -> ob ----
  {
#pragma unroll
    for (int h = 0; h < NHEAD; ++h) {
      bf16x8 a  = *(const bf16x8*)(Pb + (rt * 16 + l15) * PS + h * 32 + lg * 8);
      bf16x8 bf = *(const bf16x8*)(vT + (h * DH + l15) * VTS + lg * 8);
      f32x4 o = {};
      o = __builtin_amdgcn_mfma_f32_16x16x32_bf16(a, bf, o, 0, 0, 0);
#pragma unroll
      for (int r = 0; r < 4; ++r)
        ob[(rt * 16 + lg * 4 + r) * XS + h * DH + l15] = (short)f2bf(o[r]);
    }
  }

  // ---- stage 6: x = LN1(x + o@Wo + bo) (own rows only; no barrier needed) ----
  {
    f32x4 acc[8] = {};
    mm_mfma<8, 4>(ob + rt * 16 * XS, XS, p.wsW + 57344, 128, acc, l15, lg);
    float s[4] = {}, sq[4] = {};
#pragma unroll
    for (int ct = 0; ct < 8; ++ct) {
      int c = ct * 16 + l15;
      float bia = p.bo[c];
#pragma unroll
      for (int r = 0; r < 4; ++r) {
        int row = rt * 16 + lg * 4 + r;
        acc[ct][r] += bia + bf2f((unsigned short)xb[row * XS + c]);
        s[r] += acc[ct][r]; sq[r] += acc[ct][r] * acc[ct][r];
      }
    }
    float mean[4], inv[4];
#pragma unroll
    for (int r = 0; r < 4; ++r) {
      float S = red16_add(s[r]), SQ = red16_add(sq[r]);
      mean[r] = S * (1.0f / CH);
      float var = fmaxf(SQ * (1.0f / CH) - mean[r] * mean[r], 0.f);
      inv[r] = rsqrtf(var + 1e-5f);
    }
#pragma unroll
    for (int ct = 0; ct < 8; ++ct) {
      int c = ct * 16 + l15;
      float g = p.ln1_g[c], bt = p.ln1_b[c];
#pragma unroll
      for (int r = 0; r < 4; ++r) {
        int row = rt * 16 + lg * 4 + r;
        xb[row * XS + c] = (short)f2bf((acc[ct][r] - mean[r]) * inv[r] * g + bt);
      }
    }
  }

  // ---- stage 7: FFN + LN2 (all own-row; hb aliases kb, safe after stage-4 barrier) ----
  {
    f32x4 acc2[8] = {};
#pragma unroll
    for (int cb = 0; cb < 4; ++cb) {
      f32x4 acch[8] = {};
      mm_mfma<8, 4>(xb + rt * 16 * XS, XS, p.wsW + 73728 + cb * 128 * 128, 128,
                    acch, l15, lg);
#pragma unroll
      for (int ct = 0; ct < 8; ++ct) {
        int c = ct * 16 + l15;
        float bia = p.b1[cb * 128 + c];
#pragma unroll
        for (int r = 0; r < 4; ++r)
          hb[(rt * 16 + lg * 4 + r) * XS + c] = (short)f2bf(fmaxf(acch[ct][r] + bia, 0.f));
      }
      __syncthreads();   // conservative: ensure hb writes visible before reads
      mm_mfma<8, 4>(hb + rt * 16 * XS, XS, p.wsW + 139264 + cb * 128, 512,
                    acc2, l15, lg);
      __syncthreads();
    }
    float s[4] = {}, sq[4] = {};
#pragma unroll
    for (int ct = 0; ct < 8; ++ct) {
      int c = ct * 16 + l15;
      float bia = p.b2[c];
#pragma unroll
      for (int r = 0; r < 4; ++r) {
        int row = rt * 16 + lg * 4 + r;
        acc2[ct][r] += bia + bf2f((unsigned short)xb[row * XS + c]);
        s[r] += acc2[ct][r]; sq[r] += acc2[ct][r] * acc2[ct][r];
      }
    }
    float mean[4], inv[4];
#pragma unroll
    for (int r = 0; r < 4; ++r) {
      float S = red16_add(s[r]), SQ = red16_add(sq[r]);
      mean[r] = S * (1.0f / CH);
      float var = fmaxf(SQ * (1.0f / CH) - mean[r] * mean[r], 0.f);
      inv[r] = rsqrtf(var + 1e-5f);
    }
#pragma unroll
    for (int ct = 0; ct < 8; ++ct) {
      int c = ct * 16 + l15;
      float g = p.ln2_g[c], bt = p.ln2_b[c];
#pragma unroll
      for (int r = 0; r < 4; ++r) {
        int row = rt * 16 + lg * 4 + r;
        xb[row * XS + c] = (short)f2bf((acc2[ct][r] - mean[r]) * inv[r] * g + bt);
      }
    }
  }
  __syncthreads();

  // ---- stage 8: max-pool over K + LN(out) ----
  {
    float mx = -INFINITY;
#pragma unroll 8
    for (int r = 0; r < KNB; ++r) mx = fmaxf(mx, bf2f((unsigned short)xb[r * XS + t]));
    float s = mx, sq = mx * mx;
#pragma unroll
    for (int off = 1; off < 64; off <<= 1) {
      s  += __shfl_xor(s,  off, 64);
      sq += __shfl_xor(sq, off, 64);
    }
    if (lane == 0) { psum[rt][0] = s; psum[rt][1] = sq; }
    __syncthreads();
    float S = psum[0][0] + psum[1][0];
    float SQ = psum[0][1] + psum[1][1];
    float mean = S * (1.0f / CH);
    float var = fmaxf(SQ * (1.0f / CH) - mean * mean, 0.f);
    float inv = rsqrtf(var + 1e-5f);
    p.out[(size_t)BATCH * M_CTR * 3 + (size_t)cm * CH + t] =
        (mx - mean) * inv * p.out_g[t] + p.out_b[t];
  }
}

// ---------------------------------------------------------------------------
extern "C" void kernel_launch(void* const* d_in, const int* in_sizes, int n_in,
                              void* d_out, int out_size, void* d_ws, size_t ws_size,
                              hipStream_t stream) {
  const float* xyz     = (const float*)d_in[0];
  const float* feats   = (const float*)d_in[1];
  const float* W_in    = (const float*)d_in[2];
  const float* b_in    = (const float*)d_in[3];
  const float* ln_in_g = (const float*)d_in[4];
  const float* ln_in_b = (const float*)d_in[5];
  const float* W_pos   = (const float*)d_in[6];
  const float* b_pos   = (const float*)d_in[7];
  const float* Wq      = (const float*)d_in[8];
  const float* bq      = (const float*)d_in[9];
  const float* Wk      = (const float*)d_in[10];
  const float* bk      = (const float*)d_in[11];
  const float* Wv      = (const float*)d_in[12];
  const float* bv      = (const float*)d_in[13];
  const float* Wo      = (const float*)d_in[14];
  const float* bo      = (const float*)d_in[15];
  const float* ln1_g   = (const float*)d_in[16];
  const float* ln1_b   = (const float*)d_in[17];
  const float* W1      = (const float*)d_in[18];
  const float* b1      = (const float*)d_in[19];
  const float* W2      = (const float*)d_in[20];
  const float* b2      = (const float*)d_in[21];
  const float* ln2_g   = (const float*)d_in[22];
  const float* ln2_b   = (const float*)d_in[23];
  const float* out_g   = (const float*)d_in[24];
  const float* out_b   = (const float*)d_in[25];
  float* out = (float*)d_out;

  int* wsCtr = (int*)d_ws;                       // B*M ints
  int* wsRaw = wsCtr + BATCH * M_CTR;            // B*M*K ints
  short* wsW = (short*)(wsRaw + BATCH * M_CTR * KNB);  // 204800 bf16 weights

  prep_kernel<<<(204800 + 255) / 256, 256, 0, stream>>>(W_in, Wq, Wk, Wv, Wo,
                                                        W1, W2, wsW);
  fps_kernel<<<BATCH, 512, 0, stream>>>(xyz, wsCtr, out);
  ballq_kernel<<<(BATCH * M_CTR) / 4, 256, 0, stream>>>(xyz, wsCtr, wsRaw);

  SAParams p{xyz, feats, b_in, ln_in_g, ln_in_b, W_pos, b_pos,
             bq, bk, bv, bo, ln1_g, ln1_b, b1, b2,
             ln2_g, ln2_b, out_g, out_b,
             wsW, wsCtr, wsRaw, out};
  sa_kernel<<<BATCH * M_CTR, 128, 0, stream>>>(p);
}